// Round 1
// 741.215 us; speedup vs baseline: 1.2222x; 1.2222x over previous
//
#include <hip/hip_runtime.h>

#define N_USERS 80000
#define N_ITEMS 30000
#define N_TOTAL 110000
#define DD 64
#define NNZ_ADJ 2000000
#define NNZ_MM 300000

// ---------------- diagnostic sentinel ---------------------------------------

__global__ void k_sentinel(float* out, float v)
{
    if (threadIdx.x == 0 && blockIdx.x == 0) out[0] = v;
}

// ======================= CSR construction ===================================

__global__ void k_count_all(const int* __restrict__ ar, const int* __restrict__ ir,
                            const int* __restrict__ tr,
                            int* __restrict__ ca, int* __restrict__ ci, int* __restrict__ ct)
{
    const int total = NNZ_ADJ + 2 * NNZ_MM;
    for (int i = blockIdx.x * blockDim.x + threadIdx.x; i < total;
         i += gridDim.x * blockDim.x) {
        int r, lim; int* c;
        if (i < NNZ_ADJ)               { r = ar[i];                     c = ca; lim = N_TOTAL; }
        else if (i < NNZ_ADJ + NNZ_MM) { r = ir[i - NNZ_ADJ];           c = ci; lim = N_ITEMS; }
        else                           { r = tr[i - NNZ_ADJ - NNZ_MM];  c = ct; lim = N_ITEMS; }
        if ((unsigned)r < (unsigned)lim) atomicAdd(c + r, 1);
    }
}

struct ScanArg { const int4* cnt; int* rp; int* off; int n; };

// 3 blocks, one per matrix; 8 elems/thread via int4; n must be divisible by 8.
__global__ __launch_bounds__(1024) void k_scan(ScanArg a0, ScanArg a1, ScanArg a2)
{
    ScanArg A = (blockIdx.x == 0) ? a0 : (blockIdx.x == 1) ? a1 : a2;
    __shared__ int swav[16];
    __shared__ int carry;
    const int lane = threadIdx.x & 63;
    const int wid  = threadIdx.x >> 6;
    if (threadIdx.x == 0) carry = 0;
    __syncthreads();

    for (int base = 0; base < A.n; base += 8192) {
        const int i0 = base + threadIdx.x * 8;
        int4 va = make_int4(0, 0, 0, 0), vb = make_int4(0, 0, 0, 0);
        if (i0 < A.n) { va = A.cnt[i0 >> 2]; vb = A.cnt[(i0 >> 2) + 1]; }
        const int tsum = va.x + va.y + va.z + va.w + vb.x + vb.y + vb.z + vb.w;

        int x = tsum;
        #pragma unroll
        for (int o = 1; o < 64; o <<= 1) {
            int t = __shfl_up(x, o);
            if (lane >= o) x += t;
        }
        if (lane == 63) swav[wid] = x;
        __syncthreads();
        if (wid == 0) {
            int y = (lane < 16) ? swav[lane] : 0;
            #pragma unroll
            for (int o = 1; o < 16; o <<= 1) {
                int t = __shfl_up(y, o);
                if (lane >= o) y += t;
            }
            if (lane < 16) swav[lane] = y;
        }
        __syncthreads();
        const int wbase = (wid > 0) ? swav[wid - 1] : 0;
        int e = carry + wbase + (x - tsum);

        int4 pa, pb;
        pa.x = e;            pa.y = pa.x + va.x;  pa.z = pa.y + va.y;  pa.w = pa.z + va.z;
        pb.x = pa.w + va.w;  pb.y = pb.x + vb.x;  pb.z = pb.y + vb.y;  pb.w = pb.z + vb.z;
        if (i0 < A.n) {
            ((int4*)A.rp)[i0 >> 2]        = pa;
            ((int4*)A.rp)[(i0 >> 2) + 1]  = pb;
            ((int4*)A.off)[i0 >> 2]       = pa;
            ((int4*)A.off)[(i0 >> 2) + 1] = pb;
        }
        const int tot = swav[15];
        __syncthreads();
        if (threadIdx.x == 0) carry += tot;
        __syncthreads();
    }
    if (threadIdx.x == 0) A.rp[A.n] = carry;
}

__global__ void k_scatter_all(
    const int* __restrict__ ar, const int* __restrict__ ac, const float* __restrict__ av,
    const int* __restrict__ ir, const int* __restrict__ ic, const float* __restrict__ iv,
    const int* __restrict__ tr, const int* __restrict__ tc, const float* __restrict__ tv,
    int* __restrict__ oa, int* __restrict__ oi, int* __restrict__ ot,
    int2* __restrict__ ea, int2* __restrict__ ei, int2* __restrict__ et)
{
    const int total = NNZ_ADJ + 2 * NNZ_MM;
    for (int i = blockIdx.x * blockDim.x + threadIdx.x; i < total;
         i += gridDim.x * blockDim.x) {
        int r, c, lim; float v; int* off; int2* ep;
        if (i < NNZ_ADJ) {
            r = ar[i]; c = ac[i]; v = av[i]; off = oa; ep = ea; lim = N_TOTAL;
        } else if (i < NNZ_ADJ + NNZ_MM) {
            const int j = i - NNZ_ADJ;
            r = ir[j]; c = ic[j]; v = iv[j]; off = oi; ep = ei; lim = N_ITEMS;
        } else {
            const int j = i - NNZ_ADJ - NNZ_MM;
            r = tr[j]; c = tc[j]; v = tv[j]; off = ot; ep = et; lim = N_ITEMS;
        }
        if ((unsigned)r >= (unsigned)lim || (unsigned)c >= (unsigned)lim) continue;
        const int pos = atomicAdd(&off[r], 1);
        ep[pos] = make_int2(c, __float_as_int(v));   // single 8B store
    }
}

// ======================= CSR SpMM core ======================================
// 8-wide manually-unrolled edge loop: keeps 8 independent 256B gathers in
// flight per wave before any vmcnt wait (the dynamic-count version compiled
// to 1 load + vmcnt(0) per edge -> pure latency chain, 17% VALUBusy).

__device__ __forceinline__ float csr_row(const int* __restrict__ rp,
                                         const int2* __restrict__ ep,
                                         const float* __restrict__ xb, // x + lane
                                         int r, int lane)
{
    const int j0 = rp[r], j1 = rp[r + 1];
    float acc0 = 0.f, acc1 = 0.f;
    for (int j = j0; j < j1; j += 64) {
        const int cnt = min(64, j1 - j);
        int2 e = make_int2(0, 0);
        if (lane < cnt) e = ep[j + lane];
        int k = 0;
        for (; k + 8 <= cnt; k += 8) {
            const int c0 = __shfl(e.x, k + 0), c1 = __shfl(e.x, k + 1);
            const int c2 = __shfl(e.x, k + 2), c3 = __shfl(e.x, k + 3);
            const int c4 = __shfl(e.x, k + 4), c5 = __shfl(e.x, k + 5);
            const int c6 = __shfl(e.x, k + 6), c7 = __shfl(e.x, k + 7);
            const float v0 = __int_as_float(__shfl(e.y, k + 0));
            const float v1 = __int_as_float(__shfl(e.y, k + 1));
            const float v2 = __int_as_float(__shfl(e.y, k + 2));
            const float v3 = __int_as_float(__shfl(e.y, k + 3));
            const float v4 = __int_as_float(__shfl(e.y, k + 4));
            const float v5 = __int_as_float(__shfl(e.y, k + 5));
            const float v6 = __int_as_float(__shfl(e.y, k + 6));
            const float v7 = __int_as_float(__shfl(e.y, k + 7));
            const float x0 = xb[(size_t)c0 * DD];
            const float x1 = xb[(size_t)c1 * DD];
            const float x2 = xb[(size_t)c2 * DD];
            const float x3 = xb[(size_t)c3 * DD];
            const float x4 = xb[(size_t)c4 * DD];
            const float x5 = xb[(size_t)c5 * DD];
            const float x6 = xb[(size_t)c6 * DD];
            const float x7 = xb[(size_t)c7 * DD];
            acc0 = fmaf(v0, x0, acc0); acc1 = fmaf(v1, x1, acc1);
            acc0 = fmaf(v2, x2, acc0); acc1 = fmaf(v3, x3, acc1);
            acc0 = fmaf(v4, x4, acc0); acc1 = fmaf(v5, x5, acc1);
            acc0 = fmaf(v6, x6, acc0); acc1 = fmaf(v7, x7, acc1);
        }
        for (; k < cnt; ++k) {
            const int   ck = __shfl(e.x, k);
            const float vk = __int_as_float(__shfl(e.y, k));
            acc0 = fmaf(vk, xb[(size_t)ck * DD], acc0);
        }
    }
    return acc0 + acc1;
}

// ego variant: gather source split across user/item arrays
__device__ __forceinline__ float csr_row_ego(const int* __restrict__ rp,
                                             const int2* __restrict__ ep,
                                             const float* __restrict__ ub,
                                             const float* __restrict__ ib,
                                             int r, int lane)
{
    const int j0 = rp[r], j1 = rp[r + 1];
    float acc0 = 0.f, acc1 = 0.f;
    for (int j = j0; j < j1; j += 64) {
        const int cnt = min(64, j1 - j);
        int2 e = make_int2(0, 0);
        if (lane < cnt) e = ep[j + lane];
        int k = 0;
        for (; k + 8 <= cnt; k += 8) {
            const int c0 = __shfl(e.x, k + 0), c1 = __shfl(e.x, k + 1);
            const int c2 = __shfl(e.x, k + 2), c3 = __shfl(e.x, k + 3);
            const int c4 = __shfl(e.x, k + 4), c5 = __shfl(e.x, k + 5);
            const int c6 = __shfl(e.x, k + 6), c7 = __shfl(e.x, k + 7);
            const float v0 = __int_as_float(__shfl(e.y, k + 0));
            const float v1 = __int_as_float(__shfl(e.y, k + 1));
            const float v2 = __int_as_float(__shfl(e.y, k + 2));
            const float v3 = __int_as_float(__shfl(e.y, k + 3));
            const float v4 = __int_as_float(__shfl(e.y, k + 4));
            const float v5 = __int_as_float(__shfl(e.y, k + 5));
            const float v6 = __int_as_float(__shfl(e.y, k + 6));
            const float v7 = __int_as_float(__shfl(e.y, k + 7));
            const float* p0 = (c0 < N_USERS) ? ub + (size_t)c0 * DD : ib + (size_t)(c0 - N_USERS) * DD;
            const float* p1 = (c1 < N_USERS) ? ub + (size_t)c1 * DD : ib + (size_t)(c1 - N_USERS) * DD;
            const float* p2 = (c2 < N_USERS) ? ub + (size_t)c2 * DD : ib + (size_t)(c2 - N_USERS) * DD;
            const float* p3 = (c3 < N_USERS) ? ub + (size_t)c3 * DD : ib + (size_t)(c3 - N_USERS) * DD;
            const float* p4 = (c4 < N_USERS) ? ub + (size_t)c4 * DD : ib + (size_t)(c4 - N_USERS) * DD;
            const float* p5 = (c5 < N_USERS) ? ub + (size_t)c5 * DD : ib + (size_t)(c5 - N_USERS) * DD;
            const float* p6 = (c6 < N_USERS) ? ub + (size_t)c6 * DD : ib + (size_t)(c6 - N_USERS) * DD;
            const float* p7 = (c7 < N_USERS) ? ub + (size_t)c7 * DD : ib + (size_t)(c7 - N_USERS) * DD;
            const float x0 = *p0, x1 = *p1, x2 = *p2, x3 = *p3;
            const float x4 = *p4, x5 = *p5, x6 = *p6, x7 = *p7;
            acc0 = fmaf(v0, x0, acc0); acc1 = fmaf(v1, x1, acc1);
            acc0 = fmaf(v2, x2, acc0); acc1 = fmaf(v3, x3, acc1);
            acc0 = fmaf(v4, x4, acc0); acc1 = fmaf(v5, x5, acc1);
            acc0 = fmaf(v6, x6, acc0); acc1 = fmaf(v7, x7, acc1);
        }
        for (; k < cnt; ++k) {
            const int   ck = __shfl(e.x, k);
            const float vk = __int_as_float(__shfl(e.y, k));
            const float xv = (ck < N_USERS) ? ub[(size_t)ck * DD]
                                            : ib[(size_t)(ck - N_USERS) * DD];
            acc0 = fmaf(vk, xv, acc0);
        }
    }
    return acc0 + acc1;
}

// -------- modality SpMM + attention fused: one wave per item ----------------
// img row + txt row + softmax fuse in one pass; removes the separate
// k_mm_fuse kernel and its 23 MB of out_img/out_txt re-read traffic.

__global__ __launch_bounds__(256) void k_spmm_mm_fuse(
    const int* __restrict__ rp_i, const int2* __restrict__ ep_i,
    const int* __restrict__ rp_t, const int2* __restrict__ ep_t,
    const float* __restrict__ item_emb,
    const float* __restrict__ Wq1, const float* __restrict__ bq1, const float* __restrict__ wq2,
    float* __restrict__ out_img, float* __restrict__ out_txt, float* __restrict__ out_h)
{
    __shared__ float sW[DD * DD];
    __shared__ float sb[DD];
    __shared__ float sq[DD];
    for (int i = threadIdx.x; i < DD * DD; i += blockDim.x) sW[i] = Wq1[i];
    if (threadIdx.x < DD) {
        sb[threadIdx.x] = bq1[threadIdx.x];
        sq[threadIdx.x] = wq2[threadIdx.x];
    }
    __syncthreads();

    const int lane = threadIdx.x & 63;
    int wave       = blockIdx.x * (blockDim.x >> 6) + (threadIdx.x >> 6);
    const int nwav = gridDim.x * (blockDim.x >> 6);
    const float* xb = item_emb + lane;

    for (int i = wave; i < N_ITEMS; i += nwav) {
        const float iv = csr_row(rp_i, ep_i, xb, i, lane);
        const float tv = csr_row(rp_t, ep_t, xb, i, lane);
        const size_t base = (size_t)i * DD + lane;
        out_img[base] = iv;
        out_txt[base] = tv;

        float ai = sb[lane], at = sb[lane];
        #pragma unroll 8
        for (int k = 0; k < DD; ++k) {
            const float w = sW[k * DD + lane];
            ai += __shfl(iv, k) * w;
            at += __shfl(tv, k) * w;
        }
        float si = tanhf(ai) * sq[lane];
        float st = tanhf(at) * sq[lane];
        #pragma unroll
        for (int off = 32; off; off >>= 1) {
            si += __shfl_xor(si, off);
            st += __shfl_xor(st, off);
        }
        const float m  = fmaxf(si, st);
        const float ei = expf(si - m), et = expf(st - m);
        out_h[base] = (ei * iv + et * tv) / (ei + et);
    }
}

// cur1 = A * ego
__global__ __launch_bounds__(256) void k_spmm_ego(
    const int* __restrict__ rp, const int2* __restrict__ ep,
    const float* __restrict__ ue, const float* __restrict__ ie,
    float* __restrict__ out)
{
    const int lane = threadIdx.x & 63;
    int wave       = blockIdx.x * (blockDim.x >> 6) + (threadIdx.x >> 6);
    const int nwav = gridDim.x * (blockDim.x >> 6);
    const float* ub = ue + lane;
    const float* ib = ie + lane;
    for (int r = wave; r < N_TOTAL; r += nwav) {
        out[(size_t)r * DD + lane] = csr_row_ego(rp, ep, ub, ib, r, lane);
    }
}

// -------- fused final: cur2 row in registers + user/item epilogues ----------

__global__ __launch_bounds__(256) void k_final(
    const int* __restrict__ rp, const int2* __restrict__ ep,
    const float* __restrict__ cur1,
    const float* __restrict__ ue, const float* __restrict__ ie,
    const float* __restrict__ h_buf,
    const float* __restrict__ Wc1, const float* __restrict__ bc1, const float* __restrict__ wc2,
    float* __restrict__ out_ug, float* __restrict__ out_ig)
{
    __shared__ float sW[DD * DD];
    __shared__ float sb[DD];
    __shared__ float sq[DD];
    for (int i = threadIdx.x; i < DD * DD; i += blockDim.x) sW[i] = Wc1[i];
    if (threadIdx.x < DD) {
        sb[threadIdx.x] = bc1[threadIdx.x];
        sq[threadIdx.x] = wc2[threadIdx.x];
    }
    __syncthreads();

    const int lane = threadIdx.x & 63;
    int wave       = blockIdx.x * (blockDim.x >> 6) + (threadIdx.x >> 6);
    const int nwav = gridDim.x * (blockDim.x >> 6);
    const float* cb = cur1 + lane;

    for (int r = wave; r < N_TOTAL; r += nwav) {
        // acc = cur2 row r (A * cur1)
        const float acc = csr_row(rp, ep, cb, r, lane);
        const size_t gbase = (size_t)r * DD + lane;

        if (r < N_USERS) {
            out_ug[gbase] = (ue[gbase] + cur1[gbase] + acc) * (1.0f / 3.0f);
        } else {
            const int i = r - N_USERS;
            const size_t base = (size_t)i * DD + lane;
            const float ig = (ie[base] + cur1[gbase] + acc) * (1.0f / 3.0f);
            const float hv = h_buf[base];
            float ss = hv * hv;
            #pragma unroll
            for (int off = 32; off; off >>= 1) ss += __shfl_xor(ss, off);
            const float hn = hv / fmaxf(sqrtf(ss), 1e-12f);

            float a0 = sb[lane], a1 = sb[lane];
            #pragma unroll 8
            for (int k = 0; k < DD; ++k) {
                const float w = sW[k * DD + lane];
                a0 += __shfl(ig, k) * w;
                a1 += __shfl(hn, k) * w;
            }
            float s0 = tanhf(a0) * sq[lane];
            float s1 = tanhf(a1) * sq[lane];
            #pragma unroll
            for (int off = 32; off; off >>= 1) {
                s0 += __shfl_xor(s0, off);
                s1 += __shfl_xor(s1, off);
            }
            const float m  = fmaxf(s0, s1);
            const float e0 = expf(s0 - m), e1 = expf(s1 - m);
            out_ig[base] = (e0 * ig + e1 * hn) / (e0 + e1);
        }
    }
}

// ----------------------------------------------------------------------------

extern "C" void kernel_launch(void* const* d_in, const int* in_sizes, int n_in,
                              void* d_out, int out_size, void* d_ws, size_t ws_size,
                              hipStream_t stream)
{
    static const int EXP[17] = {
        N_USERS * DD, N_ITEMS * DD, DD * DD, DD, DD, DD * DD, DD, DD,
        NNZ_ADJ, NNZ_MM, NNZ_MM, NNZ_ADJ, NNZ_ADJ, NNZ_MM, NNZ_MM, NNZ_MM, NNZ_MM
    };

    float* out = (float*)d_out;

    const int OUT_EXPECT = (N_USERS + 4 * N_ITEMS) * DD;
    if (out_size != OUT_EXPECT) {
        k_sentinel<<<1, 64, 0, stream>>>(out, 5000.0f + (float)(((unsigned)out_size) >> 20));
        return;
    }
    if (n_in < 17) {
        k_sentinel<<<1, 64, 0, stream>>>(out, 1000.0f + 8.0f * (float)n_in);
        return;
    }

    int map[17];
    bool exact = true;
    for (int i = 0; i < 17; ++i) { map[i] = i; if (in_sizes[i] != EXP[i]) exact = false; }
    if (!exact) {
        bool used[64] = {false};
        for (int i = 0; i < 17; ++i) {
            int found = -1;
            for (int j = 0; j < n_in && j < 64; ++j)
                if (!used[j] && in_sizes[j] == EXP[i]) { found = j; break; }
            if (found < 0) {
                k_sentinel<<<1, 64, 0, stream>>>(out, 2000.0f + 32.0f * (float)i);
                return;
            }
            used[found] = true; map[i] = found;
        }
    }

    const float* user_emb = (const float*)d_in[map[0]];
    const float* item_emb = (const float*)d_in[map[1]];
    const float* Wq1      = (const float*)d_in[map[2]];
    const float* bq1      = (const float*)d_in[map[3]];
    const float* wq2      = (const float*)d_in[map[4]];
    const float* Wc1      = (const float*)d_in[map[5]];
    const float* bc1      = (const float*)d_in[map[6]];
    const float* wc2      = (const float*)d_in[map[7]];
    const float* adj_vals = (const float*)d_in[map[8]];
    const float* img_vals = (const float*)d_in[map[9]];
    const float* txt_vals = (const float*)d_in[map[10]];
    const int* adj_rows   = (const int*)d_in[map[11]];
    const int* adj_cols   = (const int*)d_in[map[12]];
    const int* img_rows   = (const int*)d_in[map[13]];
    const int* img_cols   = (const int*)d_in[map[14]];
    const int* txt_rows   = (const int*)d_in[map[15]];
    const int* txt_cols   = (const int*)d_in[map[16]];

    // -------- workspace layout (all 16B-aligned sections) --------
    float* cur1   = (float*)d_ws;                     // N_TOTAL*DD
    int2*  ep_adj = (int2*)(cur1 + (size_t)N_TOTAL * DD);
    int2*  ep_img = ep_adj + NNZ_ADJ;
    int2*  ep_txt = ep_img + NNZ_MM;
    int*   cnt_adj = (int*)(ep_txt + NNZ_MM);         // contiguous cnt block
    int*   cnt_img = cnt_adj + N_TOTAL;
    int*   cnt_txt = cnt_img + N_ITEMS;
    int*   rp_adj  = cnt_txt + N_ITEMS;               // padded to keep 16B align
    int*   rp_img  = rp_adj + 110004;
    int*   rp_txt  = rp_img + 30004;
    int*   off_adj = rp_txt + 30004;
    int*   off_img = off_adj + N_TOTAL;
    int*   off_txt = off_img + N_ITEMS;
    int*   i_end   = off_txt + N_ITEMS;

    const size_t WS_NEED = (size_t)((char*)i_end - (char*)d_ws);
    if (ws_size < WS_NEED) {
        k_sentinel<<<1, 64, 0, stream>>>(out, 3000.0f + (float)(ws_size >> 20));
        return;
    }

    float* out_ug  = out;
    float* out_ig  = out_ug  + (size_t)N_USERS * DD;
    float* out_img = out_ig  + (size_t)N_ITEMS * DD;
    float* out_txt = out_img + (size_t)N_ITEMS * DD;
    float* out_h   = out_txt + (size_t)N_ITEMS * DD;

    // ---- CSR build ----
    hipMemsetAsync(cnt_adj, 0, (size_t)(N_TOTAL + 2 * N_ITEMS) * sizeof(int), stream);
    k_count_all<<<2048, 256, 0, stream>>>(adj_rows, img_rows, txt_rows,
                                          cnt_adj, cnt_img, cnt_txt);

    ScanArg sa{(const int4*)cnt_adj, rp_adj, off_adj, N_TOTAL};
    ScanArg si{(const int4*)cnt_img, rp_img, off_img, N_ITEMS};
    ScanArg st{(const int4*)cnt_txt, rp_txt, off_txt, N_ITEMS};
    k_scan<<<3, 1024, 0, stream>>>(sa, si, st);

    k_scatter_all<<<2048, 256, 0, stream>>>(adj_rows, adj_cols, adj_vals,
                                            img_rows, img_cols, img_vals,
                                            txt_rows, txt_cols, txt_vals,
                                            off_adj, off_img, off_txt,
                                            ep_adj, ep_img, ep_txt);

    // ---- modality SpMM + attention fused -> out_img/out_txt/out_h ----
    k_spmm_mm_fuse<<<2048, 256, 0, stream>>>(rp_img, ep_img, rp_txt, ep_txt,
                                             item_emb, Wq1, bq1, wq2,
                                             out_img, out_txt, out_h);

    // ---- cur1 = A * ego ----
    k_spmm_ego<<<27500, 256, 0, stream>>>(rp_adj, ep_adj, user_emb, item_emb, cur1);

    // ---- fused: cur2 (in registers) + user/item epilogues ----
    k_final<<<2048, 256, 0, stream>>>(rp_adj, ep_adj, cur1, user_emb, item_emb,
                                      out_h, Wc1, bc1, wc2, out_ug, out_ig);
}

// Round 2
// 694.391 us; speedup vs baseline: 1.3046x; 1.0674x over previous
//
#include <hip/hip_runtime.h>

#define N_USERS 80000
#define N_ITEMS 30000
#define N_TOTAL 110000
#define DD 64
#define NNZ_ADJ 2000000
#define NNZ_MM 300000

// row-partition divisors: 8 equal partitions (8*13750 = 110000, 8*3750 = 30000)
#define PART_ADJ 13750
#define PART_MM  3750

// ---------------- diagnostic sentinel ---------------------------------------

__global__ void k_sentinel(float* out, float v)
{
    if (threadIdx.x == 0 && blockIdx.x == 0) out[0] = v;
}

// ======================= CSR construction ===================================
// XCD-partitioned: block (blockIdx%8) only counts/scatters rows in partition
// p, so each partition's counters + ep slice (~2.6 MB) live in ONE XCD's L2
// (blocks round-robin across XCDs). Kills the 8x write amplification
// (WRITE_SIZE was 162 MB for 21 MB of payload) and makes atomics L2-local.

__global__ __launch_bounds__(256) void k_count_all(
    const int* __restrict__ ar, const int* __restrict__ ir,
    const int* __restrict__ tr,
    int* __restrict__ ca, int* __restrict__ ci, int* __restrict__ ct)
{
    const int p    = blockIdx.x & 7;
    const int b8   = blockIdx.x >> 3;
    const int nb8  = gridDim.x >> 3;
    const int total = NNZ_ADJ + 2 * NNZ_MM;
    for (int i = b8 * blockDim.x + threadIdx.x; i < total;
         i += nb8 * blockDim.x) {
        int r, lim, part; int* c;
        if (i < NNZ_ADJ)               { r = ar[i];                     c = ca; lim = N_TOTAL; part = r / PART_ADJ; }
        else if (i < NNZ_ADJ + NNZ_MM) { r = ir[i - NNZ_ADJ];           c = ci; lim = N_ITEMS; part = r / PART_MM; }
        else                           { r = tr[i - NNZ_ADJ - NNZ_MM];  c = ct; lim = N_ITEMS; part = r / PART_MM; }
        if ((unsigned)r < (unsigned)lim && part == p) atomicAdd(c + r, 1);
    }
}

struct ScanArg { const int4* cnt; int* rp; int* off; int n; };

// 3 blocks, one per matrix; 8 elems/thread via int4; n must be divisible by 8.
__global__ __launch_bounds__(1024) void k_scan(ScanArg a0, ScanArg a1, ScanArg a2)
{
    ScanArg A = (blockIdx.x == 0) ? a0 : (blockIdx.x == 1) ? a1 : a2;
    __shared__ int swav[16];
    __shared__ int carry;
    const int lane = threadIdx.x & 63;
    const int wid  = threadIdx.x >> 6;
    if (threadIdx.x == 0) carry = 0;
    __syncthreads();

    for (int base = 0; base < A.n; base += 8192) {
        const int i0 = base + threadIdx.x * 8;
        int4 va = make_int4(0, 0, 0, 0), vb = make_int4(0, 0, 0, 0);
        if (i0 < A.n) { va = A.cnt[i0 >> 2]; vb = A.cnt[(i0 >> 2) + 1]; }
        const int tsum = va.x + va.y + va.z + va.w + vb.x + vb.y + vb.z + vb.w;

        int x = tsum;
        #pragma unroll
        for (int o = 1; o < 64; o <<= 1) {
            int t = __shfl_up(x, o);
            if (lane >= o) x += t;
        }
        if (lane == 63) swav[wid] = x;
        __syncthreads();
        if (wid == 0) {
            int y = (lane < 16) ? swav[lane] : 0;
            #pragma unroll
            for (int o = 1; o < 16; o <<= 1) {
                int t = __shfl_up(y, o);
                if (lane >= o) y += t;
            }
            if (lane < 16) swav[lane] = y;
        }
        __syncthreads();
        const int wbase = (wid > 0) ? swav[wid - 1] : 0;
        int e = carry + wbase + (x - tsum);

        int4 pa, pb;
        pa.x = e;            pa.y = pa.x + va.x;  pa.z = pa.y + va.y;  pa.w = pa.z + va.z;
        pb.x = pa.w + va.w;  pb.y = pb.x + vb.x;  pb.z = pb.y + vb.y;  pb.w = pb.z + vb.z;
        if (i0 < A.n) {
            ((int4*)A.rp)[i0 >> 2]        = pa;
            ((int4*)A.rp)[(i0 >> 2) + 1]  = pb;
            ((int4*)A.off)[i0 >> 2]       = pa;
            ((int4*)A.off)[(i0 >> 2) + 1] = pb;
        }
        const int tot = swav[15];
        __syncthreads();
        if (threadIdx.x == 0) carry += tot;
        __syncthreads();
    }
    if (threadIdx.x == 0) A.rp[A.n] = carry;
}

// partitioned + 4-way batched scatter: 4 atomic round-trips in flight/wave.
__global__ __launch_bounds__(256) void k_scatter_all(
    const int* __restrict__ ar, const int* __restrict__ ac, const float* __restrict__ av,
    const int* __restrict__ ir, const int* __restrict__ ic, const float* __restrict__ iv,
    const int* __restrict__ tr, const int* __restrict__ tc, const float* __restrict__ tv,
    int* __restrict__ oa, int* __restrict__ oi, int* __restrict__ ot,
    int2* __restrict__ ea, int2* __restrict__ ei, int2* __restrict__ et)
{
    const int p     = blockIdx.x & 7;
    const int b8    = blockIdx.x >> 3;
    const int nb8   = gridDim.x >> 3;
    const int total = NNZ_ADJ + 2 * NNZ_MM;
    const int step  = nb8 * blockDim.x;

    for (int i0 = b8 * blockDim.x + threadIdx.x; i0 < total; i0 += step * 4) {
        #pragma unroll
        for (int u = 0; u < 4; ++u) {
            const int i = i0 + u * step;
            if (i >= total) break;
            int r, c, lim, part; float v; int* off; int2* ep;
            if (i < NNZ_ADJ) {
                r = ar[i];
                part = r / PART_ADJ;
                if (part != p) continue;
                c = ac[i]; v = av[i]; off = oa; ep = ea; lim = N_TOTAL;
            } else if (i < NNZ_ADJ + NNZ_MM) {
                const int j = i - NNZ_ADJ;
                r = ir[j];
                part = r / PART_MM;
                if (part != p) continue;
                c = ic[j]; v = iv[j]; off = oi; ep = ei; lim = N_ITEMS;
            } else {
                const int j = i - NNZ_ADJ - NNZ_MM;
                r = tr[j];
                part = r / PART_MM;
                if (part != p) continue;
                c = tc[j]; v = tv[j]; off = ot; ep = et; lim = N_ITEMS;
            }
            if ((unsigned)r >= (unsigned)lim || (unsigned)c >= (unsigned)lim) continue;
            const int pos = atomicAdd(&off[r], 1);
            ep[pos] = make_int2(c, __float_as_int(v));   // single 8B store
        }
    }
}

// ======================= CSR SpMM core ======================================
// 8-wide manually-unrolled edge loop: keeps 8 independent 256B gathers in
// flight per wave before any vmcnt wait.

__device__ __forceinline__ float csr_row(const int* __restrict__ rp,
                                         const int2* __restrict__ ep,
                                         const float* __restrict__ xb, // x + lane
                                         int r, int lane)
{
    const int j0 = rp[r], j1 = rp[r + 1];
    float acc0 = 0.f, acc1 = 0.f;
    for (int j = j0; j < j1; j += 64) {
        const int cnt = min(64, j1 - j);
        int2 e = make_int2(0, 0);
        if (lane < cnt) e = ep[j + lane];
        int k = 0;
        for (; k + 8 <= cnt; k += 8) {
            const int c0 = __shfl(e.x, k + 0), c1 = __shfl(e.x, k + 1);
            const int c2 = __shfl(e.x, k + 2), c3 = __shfl(e.x, k + 3);
            const int c4 = __shfl(e.x, k + 4), c5 = __shfl(e.x, k + 5);
            const int c6 = __shfl(e.x, k + 6), c7 = __shfl(e.x, k + 7);
            const float v0 = __int_as_float(__shfl(e.y, k + 0));
            const float v1 = __int_as_float(__shfl(e.y, k + 1));
            const float v2 = __int_as_float(__shfl(e.y, k + 2));
            const float v3 = __int_as_float(__shfl(e.y, k + 3));
            const float v4 = __int_as_float(__shfl(e.y, k + 4));
            const float v5 = __int_as_float(__shfl(e.y, k + 5));
            const float v6 = __int_as_float(__shfl(e.y, k + 6));
            const float v7 = __int_as_float(__shfl(e.y, k + 7));
            const float x0 = xb[(size_t)c0 * DD];
            const float x1 = xb[(size_t)c1 * DD];
            const float x2 = xb[(size_t)c2 * DD];
            const float x3 = xb[(size_t)c3 * DD];
            const float x4 = xb[(size_t)c4 * DD];
            const float x5 = xb[(size_t)c5 * DD];
            const float x6 = xb[(size_t)c6 * DD];
            const float x7 = xb[(size_t)c7 * DD];
            acc0 = fmaf(v0, x0, acc0); acc1 = fmaf(v1, x1, acc1);
            acc0 = fmaf(v2, x2, acc0); acc1 = fmaf(v3, x3, acc1);
            acc0 = fmaf(v4, x4, acc0); acc1 = fmaf(v5, x5, acc1);
            acc0 = fmaf(v6, x6, acc0); acc1 = fmaf(v7, x7, acc1);
        }
        for (; k < cnt; ++k) {
            const int   ck = __shfl(e.x, k);
            const float vk = __int_as_float(__shfl(e.y, k));
            acc0 = fmaf(vk, xb[(size_t)ck * DD], acc0);
        }
    }
    return acc0 + acc1;
}

// ego variant: gather source split across user/item arrays
__device__ __forceinline__ float csr_row_ego(const int* __restrict__ rp,
                                             const int2* __restrict__ ep,
                                             const float* __restrict__ ub,
                                             const float* __restrict__ ib,
                                             int r, int lane)
{
    const int j0 = rp[r], j1 = rp[r + 1];
    float acc0 = 0.f, acc1 = 0.f;
    for (int j = j0; j < j1; j += 64) {
        const int cnt = min(64, j1 - j);
        int2 e = make_int2(0, 0);
        if (lane < cnt) e = ep[j + lane];
        int k = 0;
        for (; k + 8 <= cnt; k += 8) {
            const int c0 = __shfl(e.x, k + 0), c1 = __shfl(e.x, k + 1);
            const int c2 = __shfl(e.x, k + 2), c3 = __shfl(e.x, k + 3);
            const int c4 = __shfl(e.x, k + 4), c5 = __shfl(e.x, k + 5);
            const int c6 = __shfl(e.x, k + 6), c7 = __shfl(e.x, k + 7);
            const float v0 = __int_as_float(__shfl(e.y, k + 0));
            const float v1 = __int_as_float(__shfl(e.y, k + 1));
            const float v2 = __int_as_float(__shfl(e.y, k + 2));
            const float v3 = __int_as_float(__shfl(e.y, k + 3));
            const float v4 = __int_as_float(__shfl(e.y, k + 4));
            const float v5 = __int_as_float(__shfl(e.y, k + 5));
            const float v6 = __int_as_float(__shfl(e.y, k + 6));
            const float v7 = __int_as_float(__shfl(e.y, k + 7));
            const float* p0 = (c0 < N_USERS) ? ub + (size_t)c0 * DD : ib + (size_t)(c0 - N_USERS) * DD;
            const float* p1 = (c1 < N_USERS) ? ub + (size_t)c1 * DD : ib + (size_t)(c1 - N_USERS) * DD;
            const float* p2 = (c2 < N_USERS) ? ub + (size_t)c2 * DD : ib + (size_t)(c2 - N_USERS) * DD;
            const float* p3 = (c3 < N_USERS) ? ub + (size_t)c3 * DD : ib + (size_t)(c3 - N_USERS) * DD;
            const float* p4 = (c4 < N_USERS) ? ub + (size_t)c4 * DD : ib + (size_t)(c4 - N_USERS) * DD;
            const float* p5 = (c5 < N_USERS) ? ub + (size_t)c5 * DD : ib + (size_t)(c5 - N_USERS) * DD;
            const float* p6 = (c6 < N_USERS) ? ub + (size_t)c6 * DD : ib + (size_t)(c6 - N_USERS) * DD;
            const float* p7 = (c7 < N_USERS) ? ub + (size_t)c7 * DD : ib + (size_t)(c7 - N_USERS) * DD;
            const float x0 = *p0, x1 = *p1, x2 = *p2, x3 = *p3;
            const float x4 = *p4, x5 = *p5, x6 = *p6, x7 = *p7;
            acc0 = fmaf(v0, x0, acc0); acc1 = fmaf(v1, x1, acc1);
            acc0 = fmaf(v2, x2, acc0); acc1 = fmaf(v3, x3, acc1);
            acc0 = fmaf(v4, x4, acc0); acc1 = fmaf(v5, x5, acc1);
            acc0 = fmaf(v6, x6, acc0); acc1 = fmaf(v7, x7, acc1);
        }
        for (; k < cnt; ++k) {
            const int   ck = __shfl(e.x, k);
            const float vk = __int_as_float(__shfl(e.y, k));
            const float xv = (ck < N_USERS) ? ub[(size_t)ck * DD]
                                            : ib[(size_t)(ck - N_USERS) * DD];
            acc0 = fmaf(vk, xv, acc0);
        }
    }
    return acc0 + acc1;
}

// -------- modality SpMM + attention fused: one wave per item ----------------

__global__ __launch_bounds__(256) void k_spmm_mm_fuse(
    const int* __restrict__ rp_i, const int2* __restrict__ ep_i,
    const int* __restrict__ rp_t, const int2* __restrict__ ep_t,
    const float* __restrict__ item_emb,
    const float* __restrict__ Wq1, const float* __restrict__ bq1, const float* __restrict__ wq2,
    float* __restrict__ out_img, float* __restrict__ out_txt, float* __restrict__ out_h)
{
    __shared__ float sW[DD * DD];
    __shared__ float sb[DD];
    __shared__ float sq[DD];
    for (int i = threadIdx.x; i < DD * DD; i += blockDim.x) sW[i] = Wq1[i];
    if (threadIdx.x < DD) {
        sb[threadIdx.x] = bq1[threadIdx.x];
        sq[threadIdx.x] = wq2[threadIdx.x];
    }
    __syncthreads();

    const int lane = threadIdx.x & 63;
    int wave       = blockIdx.x * (blockDim.x >> 6) + (threadIdx.x >> 6);
    const int nwav = gridDim.x * (blockDim.x >> 6);
    const float* xb = item_emb + lane;

    for (int i = wave; i < N_ITEMS; i += nwav) {
        const float iv = csr_row(rp_i, ep_i, xb, i, lane);
        const float tv = csr_row(rp_t, ep_t, xb, i, lane);
        const size_t base = (size_t)i * DD + lane;
        out_img[base] = iv;
        out_txt[base] = tv;

        float ai = sb[lane], at = sb[lane];
        #pragma unroll 8
        for (int k = 0; k < DD; ++k) {
            const float w = sW[k * DD + lane];
            ai += __shfl(iv, k) * w;
            at += __shfl(tv, k) * w;
        }
        float si = tanhf(ai) * sq[lane];
        float st = tanhf(at) * sq[lane];
        #pragma unroll
        for (int off = 32; off; off >>= 1) {
            si += __shfl_xor(si, off);
            st += __shfl_xor(st, off);
        }
        const float m  = fmaxf(si, st);
        const float ei = expf(si - m), et = expf(st - m);
        out_h[base] = (ei * iv + et * tv) / (ei + et);
    }
}

// cur1 = A * ego
__global__ __launch_bounds__(256) void k_spmm_ego(
    const int* __restrict__ rp, const int2* __restrict__ ep,
    const float* __restrict__ ue, const float* __restrict__ ie,
    float* __restrict__ out)
{
    const int lane = threadIdx.x & 63;
    int wave       = blockIdx.x * (blockDim.x >> 6) + (threadIdx.x >> 6);
    const int nwav = gridDim.x * (blockDim.x >> 6);
    const float* ub = ue + lane;
    const float* ib = ie + lane;
    for (int r = wave; r < N_TOTAL; r += nwav) {
        out[(size_t)r * DD + lane] = csr_row_ego(rp, ep, ub, ib, r, lane);
    }
}

// -------- fused final: cur2 row in registers + user/item epilogues ----------

__global__ __launch_bounds__(256) void k_final(
    const int* __restrict__ rp, const int2* __restrict__ ep,
    const float* __restrict__ cur1,
    const float* __restrict__ ue, const float* __restrict__ ie,
    const float* __restrict__ h_buf,
    const float* __restrict__ Wc1, const float* __restrict__ bc1, const float* __restrict__ wc2,
    float* __restrict__ out_ug, float* __restrict__ out_ig)
{
    __shared__ float sW[DD * DD];
    __shared__ float sb[DD];
    __shared__ float sq[DD];
    for (int i = threadIdx.x; i < DD * DD; i += blockDim.x) sW[i] = Wc1[i];
    if (threadIdx.x < DD) {
        sb[threadIdx.x] = bc1[threadIdx.x];
        sq[threadIdx.x] = wc2[threadIdx.x];
    }
    __syncthreads();

    const int lane = threadIdx.x & 63;
    int wave       = blockIdx.x * (blockDim.x >> 6) + (threadIdx.x >> 6);
    const int nwav = gridDim.x * (blockDim.x >> 6);
    const float* cb = cur1 + lane;

    for (int r = wave; r < N_TOTAL; r += nwav) {
        // acc = cur2 row r (A * cur1)
        const float acc = csr_row(rp, ep, cb, r, lane);
        const size_t gbase = (size_t)r * DD + lane;

        if (r < N_USERS) {
            out_ug[gbase] = (ue[gbase] + cur1[gbase] + acc) * (1.0f / 3.0f);
        } else {
            const int i = r - N_USERS;
            const size_t base = (size_t)i * DD + lane;
            const float ig = (ie[base] + cur1[gbase] + acc) * (1.0f / 3.0f);
            const float hv = h_buf[base];
            float ss = hv * hv;
            #pragma unroll
            for (int off = 32; off; off >>= 1) ss += __shfl_xor(ss, off);
            const float hn = hv / fmaxf(sqrtf(ss), 1e-12f);

            float a0 = sb[lane], a1 = sb[lane];
            #pragma unroll 8
            for (int k = 0; k < DD; ++k) {
                const float w = sW[k * DD + lane];
                a0 += __shfl(ig, k) * w;
                a1 += __shfl(hn, k) * w;
            }
            float s0 = tanhf(a0) * sq[lane];
            float s1 = tanhf(a1) * sq[lane];
            #pragma unroll
            for (int off = 32; off; off >>= 1) {
                s0 += __shfl_xor(s0, off);
                s1 += __shfl_xor(s1, off);
            }
            const float m  = fmaxf(s0, s1);
            const float e0 = expf(s0 - m), e1 = expf(s1 - m);
            out_ig[base] = (e0 * ig + e1 * hn) / (e0 + e1);
        }
    }
}

// ----------------------------------------------------------------------------

extern "C" void kernel_launch(void* const* d_in, const int* in_sizes, int n_in,
                              void* d_out, int out_size, void* d_ws, size_t ws_size,
                              hipStream_t stream)
{
    static const int EXP[17] = {
        N_USERS * DD, N_ITEMS * DD, DD * DD, DD, DD, DD * DD, DD, DD,
        NNZ_ADJ, NNZ_MM, NNZ_MM, NNZ_ADJ, NNZ_ADJ, NNZ_MM, NNZ_MM, NNZ_MM, NNZ_MM
    };

    float* out = (float*)d_out;

    const int OUT_EXPECT = (N_USERS + 4 * N_ITEMS) * DD;
    if (out_size != OUT_EXPECT) {
        k_sentinel<<<1, 64, 0, stream>>>(out, 5000.0f + (float)(((unsigned)out_size) >> 20));
        return;
    }
    if (n_in < 17) {
        k_sentinel<<<1, 64, 0, stream>>>(out, 1000.0f + 8.0f * (float)n_in);
        return;
    }

    int map[17];
    bool exact = true;
    for (int i = 0; i < 17; ++i) { map[i] = i; if (in_sizes[i] != EXP[i]) exact = false; }
    if (!exact) {
        bool used[64] = {false};
        for (int i = 0; i < 17; ++i) {
            int found = -1;
            for (int j = 0; j < n_in && j < 64; ++j)
                if (!used[j] && in_sizes[j] == EXP[i]) { found = j; break; }
            if (found < 0) {
                k_sentinel<<<1, 64, 0, stream>>>(out, 2000.0f + 32.0f * (float)i);
                return;
            }
            used[found] = true; map[i] = found;
        }
    }

    const float* user_emb = (const float*)d_in[map[0]];
    const float* item_emb = (const float*)d_in[map[1]];
    const float* Wq1      = (const float*)d_in[map[2]];
    const float* bq1      = (const float*)d_in[map[3]];
    const float* wq2      = (const float*)d_in[map[4]];
    const float* Wc1      = (const float*)d_in[map[5]];
    const float* bc1      = (const float*)d_in[map[6]];
    const float* wc2      = (const float*)d_in[map[7]];
    const float* adj_vals = (const float*)d_in[map[8]];
    const float* img_vals = (const float*)d_in[map[9]];
    const float* txt_vals = (const float*)d_in[map[10]];
    const int* adj_rows   = (const int*)d_in[map[11]];
    const int* adj_cols   = (const int*)d_in[map[12]];
    const int* img_rows   = (const int*)d_in[map[13]];
    const int* img_cols   = (const int*)d_in[map[14]];
    const int* txt_rows   = (const int*)d_in[map[15]];
    const int* txt_cols   = (const int*)d_in[map[16]];

    // -------- workspace layout (all 16B-aligned sections) --------
    float* cur1   = (float*)d_ws;                     // N_TOTAL*DD
    int2*  ep_adj = (int2*)(cur1 + (size_t)N_TOTAL * DD);
    int2*  ep_img = ep_adj + NNZ_ADJ;
    int2*  ep_txt = ep_img + NNZ_MM;
    int*   cnt_adj = (int*)(ep_txt + NNZ_MM);         // contiguous cnt block
    int*   cnt_img = cnt_adj + N_TOTAL;
    int*   cnt_txt = cnt_img + N_ITEMS;
    int*   rp_adj  = cnt_txt + N_ITEMS;               // padded to keep 16B align
    int*   rp_img  = rp_adj + 110004;
    int*   rp_txt  = rp_img + 30004;
    int*   off_adj = rp_txt + 30004;
    int*   off_img = off_adj + N_TOTAL;
    int*   off_txt = off_img + N_ITEMS;
    int*   i_end   = off_txt + N_ITEMS;

    const size_t WS_NEED = (size_t)((char*)i_end - (char*)d_ws);
    if (ws_size < WS_NEED) {
        k_sentinel<<<1, 64, 0, stream>>>(out, 3000.0f + (float)(ws_size >> 20));
        return;
    }

    float* out_ug  = out;
    float* out_ig  = out_ug  + (size_t)N_USERS * DD;
    float* out_img = out_ig  + (size_t)N_ITEMS * DD;
    float* out_txt = out_img + (size_t)N_ITEMS * DD;
    float* out_h   = out_txt + (size_t)N_ITEMS * DD;

    // ---- CSR build ----
    hipMemsetAsync(cnt_adj, 0, (size_t)(N_TOTAL + 2 * N_ITEMS) * sizeof(int), stream);
    k_count_all<<<2048, 256, 0, stream>>>(adj_rows, img_rows, txt_rows,
                                          cnt_adj, cnt_img, cnt_txt);

    ScanArg sa{(const int4*)cnt_adj, rp_adj, off_adj, N_TOTAL};
    ScanArg si{(const int4*)cnt_img, rp_img, off_img, N_ITEMS};
    ScanArg st{(const int4*)cnt_txt, rp_txt, off_txt, N_ITEMS};
    k_scan<<<3, 1024, 0, stream>>>(sa, si, st);

    k_scatter_all<<<2048, 256, 0, stream>>>(adj_rows, adj_cols, adj_vals,
                                            img_rows, img_cols, img_vals,
                                            txt_rows, txt_cols, txt_vals,
                                            off_adj, off_img, off_txt,
                                            ep_adj, ep_img, ep_txt);

    // ---- modality SpMM + attention fused -> out_img/out_txt/out_h ----
    k_spmm_mm_fuse<<<2048, 256, 0, stream>>>(rp_img, ep_img, rp_txt, ep_txt,
                                             item_emb, Wq1, bq1, wq2,
                                             out_img, out_txt, out_h);

    // ---- cur1 = A * ego ----
    k_spmm_ego<<<27500, 256, 0, stream>>>(rp_adj, ep_adj, user_emb, item_emb, cur1);

    // ---- fused: cur2 (in registers) + user/item epilogues ----
    k_final<<<2048, 256, 0, stream>>>(rp_adj, ep_adj, cur1, user_emb, item_emb,
                                      out_h, Wc1, bc1, wc2, out_ug, out_ig);
}

// Round 4
// 644.023 us; speedup vs baseline: 1.4066x; 1.0782x over previous
//
#include <hip/hip_runtime.h>
#include <hip/hip_fp16.h>

#define N_USERS 80000
#define N_ITEMS 30000
#define N_TOTAL 110000
#define DD 64
#define NNZ_ADJ 2000000
#define NNZ_MM 300000

// row-partition divisors: 8 equal partitions (8*13750 = 110000, 8*3750 = 30000)
#define PART_ADJ 13750
#define PART_MM  3750

// ---------------- diagnostic sentinel ---------------------------------------

__global__ void k_sentinel(float* out, float v)
{
    if (threadIdx.x == 0 && blockIdx.x == 0) out[0] = v;
}

// ======================= CSR construction ===================================
// XCD-partitioned (round 2: WRITE_SIZE 162->~25 MB, scatter off the top-5).

__global__ __launch_bounds__(256) void k_count_all(
    const int* __restrict__ ar, const int* __restrict__ ir,
    const int* __restrict__ tr,
    int* __restrict__ ca, int* __restrict__ ci, int* __restrict__ ct)
{
    const int p    = blockIdx.x & 7;
    const int b8   = blockIdx.x >> 3;
    const int nb8  = gridDim.x >> 3;
    const int total = NNZ_ADJ + 2 * NNZ_MM;
    for (int i = b8 * blockDim.x + threadIdx.x; i < total;
         i += nb8 * blockDim.x) {
        int r, lim, part; int* c;
        if (i < NNZ_ADJ)               { r = ar[i];                     c = ca; lim = N_TOTAL; part = r / PART_ADJ; }
        else if (i < NNZ_ADJ + NNZ_MM) { r = ir[i - NNZ_ADJ];           c = ci; lim = N_ITEMS; part = r / PART_MM; }
        else                           { r = tr[i - NNZ_ADJ - NNZ_MM];  c = ct; lim = N_ITEMS; part = r / PART_MM; }
        if ((unsigned)r < (unsigned)lim && part == p) atomicAdd(c + r, 1);
    }
}

struct ScanArg { const int4* cnt; int* rp; int* off; int n; };

// 3 blocks, one per matrix; 8 elems/thread via int4; n must be divisible by 8.
__global__ __launch_bounds__(1024) void k_scan(ScanArg a0, ScanArg a1, ScanArg a2)
{
    ScanArg A = (blockIdx.x == 0) ? a0 : (blockIdx.x == 1) ? a1 : a2;
    __shared__ int swav[16];
    __shared__ int carry;
    const int lane = threadIdx.x & 63;
    const int wid  = threadIdx.x >> 6;
    if (threadIdx.x == 0) carry = 0;
    __syncthreads();

    for (int base = 0; base < A.n; base += 8192) {
        const int i0 = base + threadIdx.x * 8;
        int4 va = make_int4(0, 0, 0, 0), vb = make_int4(0, 0, 0, 0);
        if (i0 < A.n) { va = A.cnt[i0 >> 2]; vb = A.cnt[(i0 >> 2) + 1]; }
        const int tsum = va.x + va.y + va.z + va.w + vb.x + vb.y + vb.z + vb.w;

        int x = tsum;
        #pragma unroll
        for (int o = 1; o < 64; o <<= 1) {
            int t = __shfl_up(x, o);
            if (lane >= o) x += t;
        }
        if (lane == 63) swav[wid] = x;
        __syncthreads();
        if (wid == 0) {
            int y = (lane < 16) ? swav[lane] : 0;
            #pragma unroll
            for (int o = 1; o < 16; o <<= 1) {
                int t = __shfl_up(y, o);
                if (lane >= o) y += t;
            }
            if (lane < 16) swav[lane] = y;
        }
        __syncthreads();
        const int wbase = (wid > 0) ? swav[wid - 1] : 0;
        int e = carry + wbase + (x - tsum);

        int4 pa, pb;
        pa.x = e;            pa.y = pa.x + va.x;  pa.z = pa.y + va.y;  pa.w = pa.z + va.z;
        pb.x = pa.w + va.w;  pb.y = pb.x + vb.x;  pb.z = pb.y + vb.y;  pb.w = pb.z + vb.z;
        if (i0 < A.n) {
            ((int4*)A.rp)[i0 >> 2]        = pa;
            ((int4*)A.rp)[(i0 >> 2) + 1]  = pb;
            ((int4*)A.off)[i0 >> 2]       = pa;
            ((int4*)A.off)[(i0 >> 2) + 1] = pb;
        }
        const int tot = swav[15];
        __syncthreads();
        if (threadIdx.x == 0) carry += tot;
        __syncthreads();
    }
    if (threadIdx.x == 0) A.rp[A.n] = carry;
}

__global__ __launch_bounds__(256) void k_scatter_all(
    const int* __restrict__ ar, const int* __restrict__ ac, const float* __restrict__ av,
    const int* __restrict__ ir, const int* __restrict__ ic, const float* __restrict__ iv,
    const int* __restrict__ tr, const int* __restrict__ tc, const float* __restrict__ tv,
    int* __restrict__ oa, int* __restrict__ oi, int* __restrict__ ot,
    int2* __restrict__ ea, int2* __restrict__ ei, int2* __restrict__ et)
{
    const int p     = blockIdx.x & 7;
    const int b8    = blockIdx.x >> 3;
    const int nb8   = gridDim.x >> 3;
    const int total = NNZ_ADJ + 2 * NNZ_MM;
    const int step  = nb8 * blockDim.x;

    for (int i0 = b8 * blockDim.x + threadIdx.x; i0 < total; i0 += step * 4) {
        #pragma unroll
        for (int u = 0; u < 4; ++u) {
            const int i = i0 + u * step;
            if (i >= total) break;
            int r, c, lim, part; float v; int* off; int2* ep;
            if (i < NNZ_ADJ) {
                r = ar[i];
                part = r / PART_ADJ;
                if (part != p) continue;
                c = ac[i]; v = av[i]; off = oa; ep = ea; lim = N_TOTAL;
            } else if (i < NNZ_ADJ + NNZ_MM) {
                const int j = i - NNZ_ADJ;
                r = ir[j];
                part = r / PART_MM;
                if (part != p) continue;
                c = ic[j]; v = iv[j]; off = oi; ep = ei; lim = N_ITEMS;
            } else {
                const int j = i - NNZ_ADJ - NNZ_MM;
                r = tr[j];
                part = r / PART_MM;
                if (part != p) continue;
                c = tc[j]; v = tv[j]; off = ot; ep = et; lim = N_ITEMS;
            }
            if ((unsigned)r >= (unsigned)lim || (unsigned)c >= (unsigned)lim) continue;
            const int pos = atomicAdd(&off[r], 1);
            ep[pos] = make_int2(c, __float_as_int(v));   // single 8B store
        }
    }
}

// ================== fp16 helpers & gather-table abstraction =================

__device__ __forceinline__ unsigned short f2h(float f)
{
    __half h = __float2half(f);
    return *reinterpret_cast<unsigned short*>(&h);
}

struct TabF32 {
    const float* x;
    __device__ __forceinline__ TabF32 sh(int l) const { return TabF32{x + l}; }
    __device__ __forceinline__ float ld(int c) const { return x[(size_t)c * DD]; }
};
struct TabF16 {
    const __half* x;
    __device__ __forceinline__ TabF16 sh(int l) const { return TabF16{x + l}; }
    __device__ __forceinline__ float ld(int c) const { return __half2float(x[(size_t)c * DD]); }
};
struct TabEgo {   // f32 fallback for layer-1 (split user/item tables)
    const float* u; const float* it;
    __device__ __forceinline__ TabEgo sh(int l) const { return TabEgo{u + l, it + l}; }
    __device__ __forceinline__ float ld(int c) const {
        return (c < N_USERS) ? u[(size_t)c * DD] : it[(size_t)(c - N_USERS) * DD];
    }
};

// fp16 conversion of [user_emb; item_emb] -> ego16 (item slice doubles as item table)
__global__ __launch_bounds__(256) void k_cvt(const float* __restrict__ ue,
                                             const float* __restrict__ ie,
                                             unsigned short* __restrict__ out)
{
    const int n0 = N_USERS * DD / 4;
    const int n1 = N_TOTAL * DD / 4;
    for (int i = blockIdx.x * blockDim.x + threadIdx.x; i < n1;
         i += gridDim.x * blockDim.x) {
        const float4 v = (i < n0) ? ((const float4*)ue)[i] : ((const float4*)ie)[i - n0];
        ushort4 o;
        o.x = f2h(v.x); o.y = f2h(v.y); o.z = f2h(v.z); o.w = f2h(v.w);
        ((ushort4*)out)[i] = o;
    }
}

// ======================= CSR SpMM core ======================================
// Quad-row combined-range traversal: one wave owns 4 CONSECUTIVE rows and
// walks their contiguous edge range [rp[r0], rp[r0+4]) in full 64-edge
// chunks. Sub-range boundaries (wave-uniform) route edges to the right
// accumulator; every 8-slot group issues 8 gathers (invalid slots masked to
// a dummy col-0 load, shfl source clamped in-range) so no serial per-edge
// vmcnt(0) remainder remains.

template<typename T>
__device__ __forceinline__ void range8(const int2 e, int k0, int k1,
                                       const T tab, float& acc)
{
    for (int k = k0; k < k1; k += 8) {
        float vs[8], xs[8];
        #pragma unroll
        for (int s = 0; s < 8; ++s) {
            const bool ok = (k + s) < k1;           // wave-uniform
            const int  ks = ok ? (k + s) : 0;       // keep shfl src in [0,64)
            const int  cc = __shfl(e.x, ks);
            const float vv = __int_as_float(__shfl(e.y, ks));
            vs[s] = ok ? vv : 0.f;
            xs[s] = tab.ld(ok ? cc : 0);
        }
        #pragma unroll
        for (int s = 0; s < 8; ++s) acc = fmaf(vs[s], xs[s], acc);
    }
}

template<typename T>
__device__ __forceinline__ void csr_rows4(const int* __restrict__ rp,
                                          const int2* __restrict__ ep,
                                          const T tab, int r0, int lane,
                                          float& oA, float& oB, float& oC, float& oD)
{
    const int4 q = *(const int4*)(rp + r0);   // rp 16B-aligned, r0 % 4 == 0
    const int  e4 = rp[r0 + 4];
    float aA = 0.f, aB = 0.f, aC = 0.f, aD = 0.f;
    for (int j = q.x; j < e4; j += 64) {
        const int cnt = min(64, e4 - j);
        int2 e = make_int2(0, 0);
        if (lane < cnt) e = ep[j + lane];
        const int b1 = min(max(q.y - j, 0), cnt);
        const int b2 = min(max(q.z - j, 0), cnt);
        const int b3 = min(max(q.w - j, 0), cnt);
        range8(e, 0,  b1,  tab, aA);
        range8(e, b1, b2,  tab, aB);
        range8(e, b2, b3,  tab, aC);
        range8(e, b3, cnt, tab, aD);
    }
    oA = aA; oB = aB; oC = aC; oD = aD;
}

// -------- modality SpMM + attention fused: 4 items per wave -----------------

template<typename T>
__global__ __launch_bounds__(256) void k_mm_q(
    const int* __restrict__ rp_i, const int2* __restrict__ ep_i,
    const int* __restrict__ rp_t, const int2* __restrict__ ep_t,
    const T tab,
    const float* __restrict__ Wq1, const float* __restrict__ bq1, const float* __restrict__ wq2,
    float* __restrict__ out_img, float* __restrict__ out_txt, float* __restrict__ out_h)
{
    __shared__ float sW[DD * DD];
    __shared__ float sb[DD];
    __shared__ float sq[DD];
    for (int i = threadIdx.x; i < DD * DD; i += blockDim.x) sW[i] = Wq1[i];
    if (threadIdx.x < DD) {
        sb[threadIdx.x] = bq1[threadIdx.x];
        sq[threadIdx.x] = wq2[threadIdx.x];
    }
    __syncthreads();

    const int lane = threadIdx.x & 63;
    const int i0 = (blockIdx.x * 4 + (threadIdx.x >> 6)) * 4;
    if (i0 >= N_ITEMS) return;
    const T t = tab.sh(lane);

    float iv[4], tv[4];
    csr_rows4(rp_i, ep_i, t, i0, lane, iv[0], iv[1], iv[2], iv[3]);
    csr_rows4(rp_t, ep_t, t, i0, lane, tv[0], tv[1], tv[2], tv[3]);
    #pragma unroll
    for (int q = 0; q < 4; ++q) {
        const size_t p = (size_t)(i0 + q) * DD + lane;
        out_img[p] = iv[q];
        out_txt[p] = tv[q];
    }

    // 8-stream MLP (4 items x {img, txt})
    float A0[4], A1[4];
    #pragma unroll
    for (int q = 0; q < 4; ++q) { A0[q] = sb[lane]; A1[q] = sb[lane]; }
    #pragma unroll 4
    for (int k = 0; k < DD; ++k) {
        const float w = sW[k * DD + lane];
        #pragma unroll
        for (int q = 0; q < 4; ++q) {
            A0[q] = fmaf(__shfl(iv[q], k), w, A0[q]);
            A1[q] = fmaf(__shfl(tv[q], k), w, A1[q]);
        }
    }
    #pragma unroll
    for (int q = 0; q < 4; ++q) {
        float si = tanhf(A0[q]) * sq[lane];
        float st = tanhf(A1[q]) * sq[lane];
        #pragma unroll
        for (int off = 32; off; off >>= 1) {
            si += __shfl_xor(si, off);
            st += __shfl_xor(st, off);
        }
        const float m  = fmaxf(si, st);
        const float ei = expf(si - m), et = expf(st - m);
        const size_t p = (size_t)(i0 + q) * DD + lane;
        out_h[p] = (ei * iv[q] + et * tv[q]) / (ei + et);
    }
}

// -------- cur1 = A * ego, 4 rows per wave; optional fp16 shadow copy --------

template<typename T, bool W16>
__global__ __launch_bounds__(256) void k_spmm_ego_q(
    const int* __restrict__ rp, const int2* __restrict__ ep, const T tab,
    float* __restrict__ out, __half* __restrict__ out16)
{
    const int lane = threadIdx.x & 63;
    const int r0 = (blockIdx.x * 4 + (threadIdx.x >> 6)) * 4;
    if (r0 >= N_TOTAL) return;
    const T t = tab.sh(lane);
    float a, b, c, d;
    csr_rows4(rp, ep, t, r0, lane, a, b, c, d);
    const size_t p = (size_t)r0 * DD + lane;
    out[p]          = a;
    out[p + DD]     = b;
    out[p + 2 * DD] = c;
    out[p + 3 * DD] = d;
    if constexpr (W16) {
        out16[p]          = __float2half(a);
        out16[p + DD]     = __float2half(b);
        out16[p + 2 * DD] = __float2half(c);
        out16[p + 3 * DD] = __float2half(d);
    }
}

// -------- fused final: role-split blocks (item blocks first, VALU-heavy) ----

#define NB_ITEM_FINAL 1875   // 1875 blocks * 4 waves * 4 rows = 30000 items
#define NB_USER_FINAL 5000   // 5000 blocks * 4 waves * 4 rows = 80000 users

template<typename T>
__global__ __launch_bounds__(256) void k_final_q(
    const int* __restrict__ rp, const int2* __restrict__ ep, const T tab,
    const float* __restrict__ cur1,
    const float* __restrict__ ue, const float* __restrict__ ie,
    const float* __restrict__ h_buf,
    const float* __restrict__ Wc1, const float* __restrict__ bc1, const float* __restrict__ wc2,
    float* __restrict__ out_ug, float* __restrict__ out_ig)
{
    __shared__ float sW[DD * DD];
    __shared__ float sb[DD];
    __shared__ float sq[DD];
    const int lane = threadIdx.x & 63;
    const int wv   = threadIdx.x >> 6;

    if (blockIdx.x < NB_ITEM_FINAL) {
        for (int i = threadIdx.x; i < DD * DD; i += blockDim.x) sW[i] = Wc1[i];
        if (threadIdx.x < DD) {
            sb[threadIdx.x] = bc1[threadIdx.x];
            sq[threadIdx.x] = wc2[threadIdx.x];
        }
        __syncthreads();

        const int i0 = (blockIdx.x * 4 + wv) * 4;     // item index base
        const int r0 = N_USERS + i0;
        const T t = tab.sh(lane);
        float a[4];
        csr_rows4(rp, ep, t, r0, lane, a[0], a[1], a[2], a[3]);

        float ig[4], hn[4];
        #pragma unroll
        for (int q = 0; q < 4; ++q) {
            const size_t pb = (size_t)(i0 + q) * DD + lane;
            const size_t gb = (size_t)(r0 + q) * DD + lane;
            ig[q] = (ie[pb] + cur1[gb] + a[q]) * (1.0f / 3.0f);
            const float hv = h_buf[pb];
            float ss = hv * hv;
            #pragma unroll
            for (int off = 32; off; off >>= 1) ss += __shfl_xor(ss, off);
            hn[q] = hv / fmaxf(sqrtf(ss), 1e-12f);
        }

        float A0[4], A1[4];
        #pragma unroll
        for (int q = 0; q < 4; ++q) { A0[q] = sb[lane]; A1[q] = sb[lane]; }
        #pragma unroll 4
        for (int k = 0; k < DD; ++k) {
            const float w = sW[k * DD + lane];
            #pragma unroll
            for (int q = 0; q < 4; ++q) {
                A0[q] = fmaf(__shfl(ig[q], k), w, A0[q]);
                A1[q] = fmaf(__shfl(hn[q], k), w, A1[q]);
            }
        }
        #pragma unroll
        for (int q = 0; q < 4; ++q) {
            float s0 = tanhf(A0[q]) * sq[lane];
            float s1 = tanhf(A1[q]) * sq[lane];
            #pragma unroll
            for (int off = 32; off; off >>= 1) {
                s0 += __shfl_xor(s0, off);
                s1 += __shfl_xor(s1, off);
            }
            const float m  = fmaxf(s0, s1);
            const float e0 = expf(s0 - m), e1 = expf(s1 - m);
            out_ig[(size_t)(i0 + q) * DD + lane] = (e0 * ig[q] + e1 * hn[q]) / (e0 + e1);
        }
    } else {
        const int r0 = ((blockIdx.x - NB_ITEM_FINAL) * 4 + wv) * 4;   // user rows
        const T t = tab.sh(lane);
        float a[4];
        csr_rows4(rp, ep, t, r0, lane, a[0], a[1], a[2], a[3]);
        #pragma unroll
        for (int q = 0; q < 4; ++q) {
            const size_t gb = (size_t)(r0 + q) * DD + lane;
            out_ug[gb] = (ue[gb] + cur1[gb] + a[q]) * (1.0f / 3.0f);
        }
    }
}

// ----------------------------------------------------------------------------

extern "C" void kernel_launch(void* const* d_in, const int* in_sizes, int n_in,
                              void* d_out, int out_size, void* d_ws, size_t ws_size,
                              hipStream_t stream)
{
    static const int EXP[17] = {
        N_USERS * DD, N_ITEMS * DD, DD * DD, DD, DD, DD * DD, DD, DD,
        NNZ_ADJ, NNZ_MM, NNZ_MM, NNZ_ADJ, NNZ_ADJ, NNZ_MM, NNZ_MM, NNZ_MM, NNZ_MM
    };

    float* out = (float*)d_out;

    const int OUT_EXPECT = (N_USERS + 4 * N_ITEMS) * DD;
    if (out_size != OUT_EXPECT) {
        k_sentinel<<<1, 64, 0, stream>>>(out, 5000.0f + (float)(((unsigned)out_size) >> 20));
        return;
    }
    if (n_in < 17) {
        k_sentinel<<<1, 64, 0, stream>>>(out, 1000.0f + 8.0f * (float)n_in);
        return;
    }

    int map[17];
    bool exact = true;
    for (int i = 0; i < 17; ++i) { map[i] = i; if (in_sizes[i] != EXP[i]) exact = false; }
    if (!exact) {
        bool used[64] = {false};
        for (int i = 0; i < 17; ++i) {
            int found = -1;
            for (int j = 0; j < n_in && j < 64; ++j)
                if (!used[j] && in_sizes[j] == EXP[i]) { found = j; break; }
            if (found < 0) {
                k_sentinel<<<1, 64, 0, stream>>>(out, 2000.0f + 32.0f * (float)i);
                return;
            }
            used[found] = true; map[i] = found;
        }
    }

    const float* user_emb = (const float*)d_in[map[0]];
    const float* item_emb = (const float*)d_in[map[1]];
    const float* Wq1      = (const float*)d_in[map[2]];
    const float* bq1      = (const float*)d_in[map[3]];
    const float* wq2      = (const float*)d_in[map[4]];
    const float* Wc1      = (const float*)d_in[map[5]];
    const float* bc1      = (const float*)d_in[map[6]];
    const float* wc2      = (const float*)d_in[map[7]];
    const float* adj_vals = (const float*)d_in[map[8]];
    const float* img_vals = (const float*)d_in[map[9]];
    const float* txt_vals = (const float*)d_in[map[10]];
    const int* adj_rows   = (const int*)d_in[map[11]];
    const int* adj_cols   = (const int*)d_in[map[12]];
    const int* img_rows   = (const int*)d_in[map[13]];
    const int* img_cols   = (const int*)d_in[map[14]];
    const int* txt_rows   = (const int*)d_in[map[15]];
    const int* txt_cols   = (const int*)d_in[map[16]];

    // -------- workspace layout (all 16B-aligned sections) --------
    float* cur1   = (float*)d_ws;                     // N_TOTAL*DD
    int2*  ep_adj = (int2*)(cur1 + (size_t)N_TOTAL * DD);
    int2*  ep_img = ep_adj + NNZ_ADJ;
    int2*  ep_txt = ep_img + NNZ_MM;
    int*   cnt_adj = (int*)(ep_txt + NNZ_MM);         // contiguous cnt block
    int*   cnt_img = cnt_adj + N_TOTAL;
    int*   cnt_txt = cnt_img + N_ITEMS;
    int*   rp_adj  = cnt_txt + N_ITEMS;               // padded to keep 16B align
    int*   rp_img  = rp_adj + 110004;
    int*   rp_txt  = rp_img + 30004;
    int*   off_adj = rp_txt + 30004;
    int*   off_img = off_adj + N_TOTAL;
    int*   off_txt = off_img + N_ITEMS;
    int*   i_end   = off_txt + N_ITEMS;

    size_t used_b = (size_t)((char*)i_end - (char*)d_ws);
    if (ws_size < used_b) {
        k_sentinel<<<1, 64, 0, stream>>>(out, 3000.0f + (float)(ws_size >> 20));
        return;
    }
    used_b = (used_b + 15) & ~(size_t)15;
    __half* ego16 = (__half*)((char*)d_ws + used_b);          // N_TOTAL*DD halves
    __half* cur16 = ego16 + (size_t)N_TOTAL * DD;             // N_TOTAL*DD halves
    const size_t WS_FULL = used_b + 2 * (size_t)N_TOTAL * DD * sizeof(__half);
    const bool use16 = (ws_size >= WS_FULL);

    float* out_ug  = out;
    float* out_ig  = out_ug  + (size_t)N_USERS * DD;
    float* out_img = out_ig  + (size_t)N_ITEMS * DD;
    float* out_txt = out_img + (size_t)N_ITEMS * DD;
    float* out_h   = out_txt + (size_t)N_ITEMS * DD;

    // ---- CSR build ----
    hipMemsetAsync(cnt_adj, 0, (size_t)(N_TOTAL + 2 * N_ITEMS) * sizeof(int), stream);
    k_count_all<<<2048, 256, 0, stream>>>(adj_rows, img_rows, txt_rows,
                                          cnt_adj, cnt_img, cnt_txt);

    ScanArg sa{(const int4*)cnt_adj, rp_adj, off_adj, N_TOTAL};
    ScanArg si{(const int4*)cnt_img, rp_img, off_img, N_ITEMS};
    ScanArg st{(const int4*)cnt_txt, rp_txt, off_txt, N_ITEMS};
    k_scan<<<3, 1024, 0, stream>>>(sa, si, st);

    k_scatter_all<<<2048, 256, 0, stream>>>(adj_rows, adj_cols, adj_vals,
                                            img_rows, img_cols, img_vals,
                                            txt_rows, txt_cols, txt_vals,
                                            off_adj, off_img, off_txt,
                                            ep_adj, ep_img, ep_txt);

    if (use16) {
        // fp16 gather tables: halve the L2-miss bytes on every SpMM gather
        k_cvt<<<2048, 256, 0, stream>>>(user_emb, item_emb, (unsigned short*)ego16);

        k_mm_q<TabF16><<<1875, 256, 0, stream>>>(
            rp_img, ep_img, rp_txt, ep_txt,
            TabF16{ego16 + (size_t)N_USERS * DD},
            Wq1, bq1, wq2, out_img, out_txt, out_h);

        k_spmm_ego_q<TabF16, true><<<6875, 256, 0, stream>>>(
            rp_adj, ep_adj, TabF16{ego16}, cur1, cur16);

        k_final_q<TabF16><<<NB_ITEM_FINAL + NB_USER_FINAL, 256, 0, stream>>>(
            rp_adj, ep_adj, TabF16{cur16}, cur1, user_emb, item_emb,
            out_h, Wc1, bc1, wc2, out_ug, out_ig);
    } else {
        // f32 fallback (quad traversal only)
        k_mm_q<TabF32><<<1875, 256, 0, stream>>>(
            rp_img, ep_img, rp_txt, ep_txt, TabF32{item_emb},
            Wq1, bq1, wq2, out_img, out_txt, out_h);

        k_spmm_ego_q<TabEgo, false><<<6875, 256, 0, stream>>>(
            rp_adj, ep_adj, TabEgo{user_emb, item_emb}, cur1, nullptr);

        k_final_q<TabF32><<<NB_ITEM_FINAL + NB_USER_FINAL, 256, 0, stream>>>(
            rp_adj, ep_adj, TabF32{cur1}, cur1, user_emb, item_emb,
            out_h, Wc1, bc1, wc2, out_ug, out_ig);
    }
}

// Round 5
// 622.986 us; speedup vs baseline: 1.4541x; 1.0338x over previous
//
#include <hip/hip_runtime.h>
#include <hip/hip_fp16.h>

#define N_USERS 80000
#define N_ITEMS 30000
#define N_TOTAL 110000
#define DD 64
#define NNZ_ADJ 2000000
#define NNZ_MM 300000

// row-partition divisors: 8 equal partitions (8*13750 = 110000, 8*3750 = 30000)
#define PART_ADJ 13750
#define PART_MM  3750

typedef float          f32x4 __attribute__((ext_vector_type(4)));
typedef unsigned short u16x4 __attribute__((ext_vector_type(4)));

// ---------------- non-temporal access helpers -------------------------------
// Streaming (read-once / write-once) data must NOT allocate L2: the L2 is
// reserved for the two things with reuse — the scatter's partially-written ep
// lines and the SpMM gather tables. (Round-4 scatter: WRITE_SIZE 144 MB for
// 21 MB payload = dirty-line eviction by the kernel's own 121 MB read stream.)

__device__ __forceinline__ int   ntl(const int* p)   { return __builtin_nontemporal_load(p); }
__device__ __forceinline__ float ntl(const float* p) { return __builtin_nontemporal_load(p); }
__device__ __forceinline__ int2  ntl2(const int2* p)
{
    union { long long l; int2 v; } u;
    u.l = __builtin_nontemporal_load(reinterpret_cast<const long long*>(p));
    return u.v;
}
__device__ __forceinline__ void nts(float* p, float v) { __builtin_nontemporal_store(v, p); }

__device__ __forceinline__ unsigned short f2h(float f)
{
    __half h = __float2half(f);
    return *reinterpret_cast<unsigned short*>(&h);
}
__device__ __forceinline__ void nts_h(__half* p, float f)
{
    __builtin_nontemporal_store(f2h(f), reinterpret_cast<unsigned short*>(p));
}

// ---------------- diagnostic sentinel ---------------------------------------

__global__ void k_sentinel(float* out, float v)
{
    if (threadIdx.x == 0 && blockIdx.x == 0) out[0] = v;
}

// ======================= CSR construction ===================================

// single pass, NT reads; counters (680 KB) live in L2, atomics are L2-local
__global__ __launch_bounds__(256) void k_count_all(
    const int* __restrict__ ar, const int* __restrict__ ir,
    const int* __restrict__ tr,
    int* __restrict__ ca, int* __restrict__ ci, int* __restrict__ ct)
{
    const int total = NNZ_ADJ + 2 * NNZ_MM;
    for (int i = blockIdx.x * blockDim.x + threadIdx.x; i < total;
         i += gridDim.x * blockDim.x) {
        int r, lim; int* c;
        if (i < NNZ_ADJ)               { r = ntl(ar + i);                    c = ca; lim = N_TOTAL; }
        else if (i < NNZ_ADJ + NNZ_MM) { r = ntl(ir + (i - NNZ_ADJ));        c = ci; lim = N_ITEMS; }
        else                           { r = ntl(tr + (i - NNZ_ADJ - NNZ_MM)); c = ct; lim = N_ITEMS; }
        if ((unsigned)r < (unsigned)lim) atomicAdd(c + r, 1);
    }
}

struct ScanArg { const int4* cnt; int* rp; int* off; int n; };

// 3 blocks, one per matrix; 8 elems/thread via int4; n must be divisible by 8.
__global__ __launch_bounds__(1024) void k_scan(ScanArg a0, ScanArg a1, ScanArg a2)
{
    ScanArg A = (blockIdx.x == 0) ? a0 : (blockIdx.x == 1) ? a1 : a2;
    __shared__ int swav[16];
    __shared__ int carry;
    const int lane = threadIdx.x & 63;
    const int wid  = threadIdx.x >> 6;
    if (threadIdx.x == 0) carry = 0;
    __syncthreads();

    for (int base = 0; base < A.n; base += 8192) {
        const int i0 = base + threadIdx.x * 8;
        int4 va = make_int4(0, 0, 0, 0), vb = make_int4(0, 0, 0, 0);
        if (i0 < A.n) { va = A.cnt[i0 >> 2]; vb = A.cnt[(i0 >> 2) + 1]; }
        const int tsum = va.x + va.y + va.z + va.w + vb.x + vb.y + vb.z + vb.w;

        int x = tsum;
        #pragma unroll
        for (int o = 1; o < 64; o <<= 1) {
            int t = __shfl_up(x, o);
            if (lane >= o) x += t;
        }
        if (lane == 63) swav[wid] = x;
        __syncthreads();
        if (wid == 0) {
            int y = (lane < 16) ? swav[lane] : 0;
            #pragma unroll
            for (int o = 1; o < 16; o <<= 1) {
                int t = __shfl_up(y, o);
                if (lane >= o) y += t;
            }
            if (lane < 16) swav[lane] = y;
        }
        __syncthreads();
        const int wbase = (wid > 0) ? swav[wid - 1] : 0;
        int e = carry + wbase + (x - tsum);

        int4 pa, pb;
        pa.x = e;            pa.y = pa.x + va.x;  pa.z = pa.y + va.y;  pa.w = pa.z + va.z;
        pb.x = pa.w + va.w;  pb.y = pb.x + vb.x;  pb.z = pb.y + vb.y;  pb.w = pb.z + vb.z;
        if (i0 < A.n) {
            ((int4*)A.rp)[i0 >> 2]        = pa;
            ((int4*)A.rp)[(i0 >> 2) + 1]  = pb;
            ((int4*)A.off)[i0 >> 2]       = pa;
            ((int4*)A.off)[(i0 >> 2) + 1] = pb;
        }
        const int tot = swav[15];
        __syncthreads();
        if (threadIdx.x == 0) carry += tot;
        __syncthreads();
    }
    if (threadIdx.x == 0) A.rp[A.n] = carry;
}

// partitioned (write locality) + 4-way batched + NT reads.
// ep stores stay CACHED: with NT reads not allocating, each partition's
// 2.6 MB ep slice stays resident in its XCD's L2 and lines fill before
// writeback.
__global__ __launch_bounds__(256) void k_scatter_all(
    const int* __restrict__ ar, const int* __restrict__ ac, const float* __restrict__ av,
    const int* __restrict__ ir, const int* __restrict__ ic, const float* __restrict__ iv,
    const int* __restrict__ tr, const int* __restrict__ tc, const float* __restrict__ tv,
    int* __restrict__ oa, int* __restrict__ oi, int* __restrict__ ot,
    int2* __restrict__ ea, int2* __restrict__ ei, int2* __restrict__ et)
{
    const int p     = blockIdx.x & 7;
    const int b8    = blockIdx.x >> 3;
    const int nb8   = gridDim.x >> 3;
    const int total = NNZ_ADJ + 2 * NNZ_MM;
    const int step  = nb8 * blockDim.x;

    for (int i0 = b8 * blockDim.x + threadIdx.x; i0 < total; i0 += step * 4) {
        #pragma unroll
        for (int u = 0; u < 4; ++u) {
            const int i = i0 + u * step;
            if (i >= total) break;
            int r, c, lim, part; float v; int* off; int2* ep;
            if (i < NNZ_ADJ) {
                r = ntl(ar + i);
                part = r / PART_ADJ;
                if (part != p) continue;
                c = ntl(ac + i); v = ntl(av + i); off = oa; ep = ea; lim = N_TOTAL;
            } else if (i < NNZ_ADJ + NNZ_MM) {
                const int j = i - NNZ_ADJ;
                r = ntl(ir + j);
                part = r / PART_MM;
                if (part != p) continue;
                c = ntl(ic + j); v = ntl(iv + j); off = oi; ep = ei; lim = N_ITEMS;
            } else {
                const int j = i - NNZ_ADJ - NNZ_MM;
                r = ntl(tr + j);
                part = r / PART_MM;
                if (part != p) continue;
                c = ntl(tc + j); v = ntl(tv + j); off = ot; ep = et; lim = N_ITEMS;
            }
            if ((unsigned)r >= (unsigned)lim || (unsigned)c >= (unsigned)lim) continue;
            const int pos = atomicAdd(&off[r], 1);
            ep[pos] = make_int2(c, __float_as_int(v));   // cached 8B store
        }
    }
}

// ================== gather-table abstraction ================================
// Table loads stay CACHED — the tables are the only data with reuse.

struct TabF32 {
    const float* x;
    __device__ __forceinline__ TabF32 sh(int l) const { return TabF32{x + l}; }
    __device__ __forceinline__ float ld(int c) const { return x[(size_t)c * DD]; }
};
struct TabF16 {
    const __half* x;
    __device__ __forceinline__ TabF16 sh(int l) const { return TabF16{x + l}; }
    __device__ __forceinline__ float ld(int c) const { return __half2float(x[(size_t)c * DD]); }
};
struct TabEgo {   // f32 fallback for layer-1 (split user/item tables)
    const float* u; const float* it;
    __device__ __forceinline__ TabEgo sh(int l) const { return TabEgo{u + l, it + l}; }
    __device__ __forceinline__ float ld(int c) const {
        return (c < N_USERS) ? u[(size_t)c * DD] : it[(size_t)(c - N_USERS) * DD];
    }
};

// fp16 conversion of [user_emb; item_emb] -> ego16 (item slice doubles as item table)
__global__ __launch_bounds__(256) void k_cvt(const float* __restrict__ ue,
                                             const float* __restrict__ ie,
                                             unsigned short* __restrict__ out)
{
    const int n0 = N_USERS * DD / 4;
    const int n1 = N_TOTAL * DD / 4;
    for (int i = blockIdx.x * blockDim.x + threadIdx.x; i < n1;
         i += gridDim.x * blockDim.x) {
        const f32x4 v = (i < n0)
            ? __builtin_nontemporal_load(((const f32x4*)ue) + i)
            : __builtin_nontemporal_load(((const f32x4*)ie) + (i - n0));
        u16x4 o;
        o.x = f2h(v.x); o.y = f2h(v.y); o.z = f2h(v.z); o.w = f2h(v.w);
        __builtin_nontemporal_store(o, ((u16x4*)out) + i);
    }
}

// ======================= CSR SpMM core ======================================
// Quad-row combined-range traversal (round 4). ep chunk loads are NT
// (read-once 16 MB stream — keep it out of the gather table's L2).

template<typename T>
__device__ __forceinline__ void range8(const int2 e, int k0, int k1,
                                       const T tab, float& acc)
{
    for (int k = k0; k < k1; k += 8) {
        float vs[8], xs[8];
        #pragma unroll
        for (int s = 0; s < 8; ++s) {
            const bool ok = (k + s) < k1;           // wave-uniform
            const int  ks = ok ? (k + s) : 0;       // keep shfl src in [0,64)
            const int  cc = __shfl(e.x, ks);
            const float vv = __int_as_float(__shfl(e.y, ks));
            vs[s] = ok ? vv : 0.f;
            xs[s] = tab.ld(ok ? cc : 0);
        }
        #pragma unroll
        for (int s = 0; s < 8; ++s) acc = fmaf(vs[s], xs[s], acc);
    }
}

template<typename T>
__device__ __forceinline__ void csr_rows4(const int* __restrict__ rp,
                                          const int2* __restrict__ ep,
                                          const T tab, int r0, int lane,
                                          float& oA, float& oB, float& oC, float& oD)
{
    const int4 q = *(const int4*)(rp + r0);   // rp 16B-aligned, r0 % 4 == 0
    const int  e4 = rp[r0 + 4];
    float aA = 0.f, aB = 0.f, aC = 0.f, aD = 0.f;
    for (int j = q.x; j < e4; j += 64) {
        const int cnt = min(64, e4 - j);
        int2 e = make_int2(0, 0);
        if (lane < cnt) e = ntl2(ep + j + lane);
        const int b1 = min(max(q.y - j, 0), cnt);
        const int b2 = min(max(q.z - j, 0), cnt);
        const int b3 = min(max(q.w - j, 0), cnt);
        range8(e, 0,  b1,  tab, aA);
        range8(e, b1, b2,  tab, aB);
        range8(e, b2, b3,  tab, aC);
        range8(e, b3, cnt, tab, aD);
    }
    oA = aA; oB = aB; oC = aC; oD = aD;
}

// -------- modality SpMM + attention fused: 4 items per wave -----------------

template<typename T>
__global__ __launch_bounds__(256) void k_mm_q(
    const int* __restrict__ rp_i, const int2* __restrict__ ep_i,
    const int* __restrict__ rp_t, const int2* __restrict__ ep_t,
    const T tab,
    const float* __restrict__ Wq1, const float* __restrict__ bq1, const float* __restrict__ wq2,
    float* __restrict__ out_img, float* __restrict__ out_txt, float* __restrict__ out_h)
{
    __shared__ float sW[DD * DD];
    __shared__ float sb[DD];
    __shared__ float sq[DD];
    for (int i = threadIdx.x; i < DD * DD; i += blockDim.x) sW[i] = Wq1[i];
    if (threadIdx.x < DD) {
        sb[threadIdx.x] = bq1[threadIdx.x];
        sq[threadIdx.x] = wq2[threadIdx.x];
    }
    __syncthreads();

    const int lane = threadIdx.x & 63;
    const int i0 = (blockIdx.x * 4 + (threadIdx.x >> 6)) * 4;
    if (i0 >= N_ITEMS) return;
    const T t = tab.sh(lane);

    float iv[4], tv[4];
    csr_rows4(rp_i, ep_i, t, i0, lane, iv[0], iv[1], iv[2], iv[3]);
    csr_rows4(rp_t, ep_t, t, i0, lane, tv[0], tv[1], tv[2], tv[3]);
    #pragma unroll
    for (int q = 0; q < 4; ++q) {
        const size_t p = (size_t)(i0 + q) * DD + lane;
        nts(out_img + p, iv[q]);
        nts(out_txt + p, tv[q]);
    }

    // 8-stream MLP (4 items x {img, txt})
    float A0[4], A1[4];
    #pragma unroll
    for (int q = 0; q < 4; ++q) { A0[q] = sb[lane]; A1[q] = sb[lane]; }
    #pragma unroll 4
    for (int k = 0; k < DD; ++k) {
        const float w = sW[k * DD + lane];
        #pragma unroll
        for (int q = 0; q < 4; ++q) {
            A0[q] = fmaf(__shfl(iv[q], k), w, A0[q]);
            A1[q] = fmaf(__shfl(tv[q], k), w, A1[q]);
        }
    }
    #pragma unroll
    for (int q = 0; q < 4; ++q) {
        float si = tanhf(A0[q]) * sq[lane];
        float st = tanhf(A1[q]) * sq[lane];
        #pragma unroll
        for (int off = 32; off; off >>= 1) {
            si += __shfl_xor(si, off);
            st += __shfl_xor(st, off);
        }
        const float m  = fmaxf(si, st);
        const float ei = expf(si - m), et = expf(st - m);
        const size_t p = (size_t)(i0 + q) * DD + lane;
        nts(out_h + p, (ei * iv[q] + et * tv[q]) / (ei + et));
    }
}

// -------- cur1 = A * ego, 4 rows per wave; optional fp16 shadow copy --------

template<typename T, bool W16>
__global__ __launch_bounds__(256) void k_spmm_ego_q(
    const int* __restrict__ rp, const int2* __restrict__ ep, const T tab,
    float* __restrict__ out, __half* __restrict__ out16)
{
    const int lane = threadIdx.x & 63;
    const int r0 = (blockIdx.x * 4 + (threadIdx.x >> 6)) * 4;
    if (r0 >= N_TOTAL) return;
    const T t = tab.sh(lane);
    float a, b, c, d;
    csr_rows4(rp, ep, t, r0, lane, a, b, c, d);
    const size_t p = (size_t)r0 * DD + lane;
    nts(out + p,          a);
    nts(out + p + DD,     b);
    nts(out + p + 2 * DD, c);
    nts(out + p + 3 * DD, d);
    if constexpr (W16) {
        nts_h(out16 + p,          a);
        nts_h(out16 + p + DD,     b);
        nts_h(out16 + p + 2 * DD, c);
        nts_h(out16 + p + 3 * DD, d);
    }
}

// -------- fused final: role-split blocks (item blocks first, VALU-heavy) ----

#define NB_ITEM_FINAL 1875   // 1875 blocks * 4 waves * 4 rows = 30000 items
#define NB_USER_FINAL 5000   // 5000 blocks * 4 waves * 4 rows = 80000 users

template<typename T>
__global__ __launch_bounds__(256) void k_final_q(
    const int* __restrict__ rp, const int2* __restrict__ ep, const T tab,
    const float* __restrict__ cur1,
    const float* __restrict__ ue, const float* __restrict__ ie,
    const float* __restrict__ h_buf,
    const float* __restrict__ Wc1, const float* __restrict__ bc1, const float* __restrict__ wc2,
    float* __restrict__ out_ug, float* __restrict__ out_ig)
{
    __shared__ float sW[DD * DD];
    __shared__ float sb[DD];
    __shared__ float sq[DD];
    const int lane = threadIdx.x & 63;
    const int wv   = threadIdx.x >> 6;

    if (blockIdx.x < NB_ITEM_FINAL) {
        for (int i = threadIdx.x; i < DD * DD; i += blockDim.x) sW[i] = Wc1[i];
        if (threadIdx.x < DD) {
            sb[threadIdx.x] = bc1[threadIdx.x];
            sq[threadIdx.x] = wc2[threadIdx.x];
        }
        __syncthreads();

        const int i0 = (blockIdx.x * 4 + wv) * 4;     // item index base
        const int r0 = N_USERS + i0;
        const T t = tab.sh(lane);
        float a[4];
        csr_rows4(rp, ep, t, r0, lane, a[0], a[1], a[2], a[3]);

        float ig[4], hn[4];
        #pragma unroll
        for (int q = 0; q < 4; ++q) {
            const size_t pb = (size_t)(i0 + q) * DD + lane;
            const size_t gb = (size_t)(r0 + q) * DD + lane;
            ig[q] = (ntl(ie + pb) + ntl(cur1 + gb) + a[q]) * (1.0f / 3.0f);
            const float hv = ntl(h_buf + pb);
            float ss = hv * hv;
            #pragma unroll
            for (int off = 32; off; off >>= 1) ss += __shfl_xor(ss, off);
            hn[q] = hv / fmaxf(sqrtf(ss), 1e-12f);
        }

        float A0[4], A1[4];
        #pragma unroll
        for (int q = 0; q < 4; ++q) { A0[q] = sb[lane]; A1[q] = sb[lane]; }
        #pragma unroll 4
        for (int k = 0; k < DD; ++k) {
            const float w = sW[k * DD + lane];
            #pragma unroll
            for (int q = 0; q < 4; ++q) {
                A0[q] = fmaf(__shfl(ig[q], k), w, A0[q]);
                A1[q] = fmaf(__shfl(hn[q], k), w, A1[q]);
            }
        }
        #pragma unroll
        for (int q = 0; q < 4; ++q) {
            float s0 = tanhf(A0[q]) * sq[lane];
            float s1 = tanhf(A1[q]) * sq[lane];
            #pragma unroll
            for (int off = 32; off; off >>= 1) {
                s0 += __shfl_xor(s0, off);
                s1 += __shfl_xor(s1, off);
            }
            const float m  = fmaxf(s0, s1);
            const float e0 = expf(s0 - m), e1 = expf(s1 - m);
            nts(out_ig + (size_t)(i0 + q) * DD + lane,
                (e0 * ig[q] + e1 * hn[q]) / (e0 + e1));
        }
    } else {
        const int r0 = ((blockIdx.x - NB_ITEM_FINAL) * 4 + wv) * 4;   // user rows
        const T t = tab.sh(lane);
        float a[4];
        csr_rows4(rp, ep, t, r0, lane, a[0], a[1], a[2], a[3]);
        #pragma unroll
        for (int q = 0; q < 4; ++q) {
            const size_t gb = (size_t)(r0 + q) * DD + lane;
            nts(out_ug + gb, (ntl(ue + gb) + ntl(cur1 + gb) + a[q]) * (1.0f / 3.0f));
        }
    }
}

// ----------------------------------------------------------------------------

extern "C" void kernel_launch(void* const* d_in, const int* in_sizes, int n_in,
                              void* d_out, int out_size, void* d_ws, size_t ws_size,
                              hipStream_t stream)
{
    static const int EXP[17] = {
        N_USERS * DD, N_ITEMS * DD, DD * DD, DD, DD, DD * DD, DD, DD,
        NNZ_ADJ, NNZ_MM, NNZ_MM, NNZ_ADJ, NNZ_ADJ, NNZ_MM, NNZ_MM, NNZ_MM, NNZ_MM
    };

    float* out = (float*)d_out;

    const int OUT_EXPECT = (N_USERS + 4 * N_ITEMS) * DD;
    if (out_size != OUT_EXPECT) {
        k_sentinel<<<1, 64, 0, stream>>>(out, 5000.0f + (float)(((unsigned)out_size) >> 20));
        return;
    }
    if (n_in < 17) {
        k_sentinel<<<1, 64, 0, stream>>>(out, 1000.0f + 8.0f * (float)n_in);
        return;
    }

    int map[17];
    bool exact = true;
    for (int i = 0; i < 17; ++i) { map[i] = i; if (in_sizes[i] != EXP[i]) exact = false; }
    if (!exact) {
        bool used[64] = {false};
        for (int i = 0; i < 17; ++i) {
            int found = -1;
            for (int j = 0; j < n_in && j < 64; ++j)
                if (!used[j] && in_sizes[j] == EXP[i]) { found = j; break; }
            if (found < 0) {
                k_sentinel<<<1, 64, 0, stream>>>(out, 2000.0f + 32.0f * (float)i);
                return;
            }
            used[found] = true; map[i] = found;
        }
    }

    const float* user_emb = (const float*)d_in[map[0]];
    const float* item_emb = (const float*)d_in[map[1]];
    const float* Wq1      = (const float*)d_in[map[2]];
    const float* bq1      = (const float*)d_in[map[3]];
    const float* wq2      = (const float*)d_in[map[4]];
    const float* Wc1      = (const float*)d_in[map[5]];
    const float* bc1      = (const float*)d_in[map[6]];
    const float* wc2      = (const float*)d_in[map[7]];
    const float* adj_vals = (const float*)d_in[map[8]];
    const float* img_vals = (const float*)d_in[map[9]];
    const float* txt_vals = (const float*)d_in[map[10]];
    const int* adj_rows   = (const int*)d_in[map[11]];
    const int* adj_cols   = (const int*)d_in[map[12]];
    const int* img_rows   = (const int*)d_in[map[13]];
    const int* img_cols   = (const int*)d_in[map[14]];
    const int* txt_rows   = (const int*)d_in[map[15]];
    const int* txt_cols   = (const int*)d_in[map[16]];

    // -------- workspace layout (all 16B-aligned sections) --------
    float* cur1   = (float*)d_ws;                     // N_TOTAL*DD
    int2*  ep_adj = (int2*)(cur1 + (size_t)N_TOTAL * DD);
    int2*  ep_img = ep_adj + NNZ_ADJ;
    int2*  ep_txt = ep_img + NNZ_MM;
    int*   cnt_adj = (int*)(ep_txt + NNZ_MM);         // contiguous cnt block
    int*   cnt_img = cnt_adj + N_TOTAL;
    int*   cnt_txt = cnt_img + N_ITEMS;
    int*   rp_adj  = cnt_txt + N_ITEMS;               // padded to keep 16B align
    int*   rp_img  = rp_adj + 110004;
    int*   rp_txt  = rp_img + 30004;
    int*   off_adj = rp_txt + 30004;
    int*   off_img = off_adj + N_TOTAL;
    int*   off_txt = off_img + N_ITEMS;
    int*   i_end   = off_txt + N_ITEMS;

    size_t used_b = (size_t)((char*)i_end - (char*)d_ws);
    if (ws_size < used_b) {
        k_sentinel<<<1, 64, 0, stream>>>(out, 3000.0f + (float)(ws_size >> 20));
        return;
    }
    used_b = (used_b + 15) & ~(size_t)15;
    __half* ego16 = (__half*)((char*)d_ws + used_b);          // N_TOTAL*DD halves
    __half* cur16 = ego16 + (size_t)N_TOTAL * DD;             // N_TOTAL*DD halves
    const size_t WS_FULL = used_b + 2 * (size_t)N_TOTAL * DD * sizeof(__half);
    const bool use16 = (ws_size >= WS_FULL);

    float* out_ug  = out;
    float* out_ig  = out_ug  + (size_t)N_USERS * DD;
    float* out_img = out_ig  + (size_t)N_ITEMS * DD;
    float* out_txt = out_img + (size_t)N_ITEMS * DD;
    float* out_h   = out_txt + (size_t)N_ITEMS * DD;

    // ---- CSR build ----
    hipMemsetAsync(cnt_adj, 0, (size_t)(N_TOTAL + 2 * N_ITEMS) * sizeof(int), stream);
    k_count_all<<<2048, 256, 0, stream>>>(adj_rows, img_rows, txt_rows,
                                          cnt_adj, cnt_img, cnt_txt);

    ScanArg sa{(const int4*)cnt_adj, rp_adj, off_adj, N_TOTAL};
    ScanArg si{(const int4*)cnt_img, rp_img, off_img, N_ITEMS};
    ScanArg st{(const int4*)cnt_txt, rp_txt, off_txt, N_ITEMS};
    k_scan<<<3, 1024, 0, stream>>>(sa, si, st);

    k_scatter_all<<<2048, 256, 0, stream>>>(adj_rows, adj_cols, adj_vals,
                                            img_rows, img_cols, img_vals,
                                            txt_rows, txt_cols, txt_vals,
                                            off_adj, off_img, off_txt,
                                            ep_adj, ep_img, ep_txt);

    if (use16) {
        // fp16 gather tables: halve the L2-miss bytes on every SpMM gather
        k_cvt<<<2048, 256, 0, stream>>>(user_emb, item_emb, (unsigned short*)ego16);

        k_mm_q<TabF16><<<1875, 256, 0, stream>>>(
            rp_img, ep_img, rp_txt, ep_txt,
            TabF16{ego16 + (size_t)N_USERS * DD},
            Wq1, bq1, wq2, out_img, out_txt, out_h);

        k_spmm_ego_q<TabF16, true><<<6875, 256, 0, stream>>>(
            rp_adj, ep_adj, TabF16{ego16}, cur1, cur16);

        k_final_q<TabF16><<<NB_ITEM_FINAL + NB_USER_FINAL, 256, 0, stream>>>(
            rp_adj, ep_adj, TabF16{cur16}, cur1, user_emb, item_emb,
            out_h, Wc1, bc1, wc2, out_ug, out_ig);
    } else {
        // f32 fallback (quad traversal only)
        k_mm_q<TabF32><<<1875, 256, 0, stream>>>(
            rp_img, ep_img, rp_txt, ep_txt, TabF32{item_emb},
            Wq1, bq1, wq2, out_img, out_txt, out_h);

        k_spmm_ego_q<TabEgo, false><<<6875, 256, 0, stream>>>(
            rp_adj, ep_adj, TabEgo{user_emb, item_emb}, cur1, nullptr);

        k_final_q<TabF32><<<NB_ITEM_FINAL + NB_USER_FINAL, 256, 0, stream>>>(
            rp_adj, ep_adj, TabF32{cur1}, cur1, user_emb, item_emb,
            out_h, Wc1, bc1, wc2, out_ug, out_ig);
    }
}

// Round 6
// 586.605 us; speedup vs baseline: 1.5443x; 1.0620x over previous
//
#include <hip/hip_runtime.h>
#include <hip/hip_fp16.h>

#define N_USERS 80000
#define N_ITEMS 30000
#define N_TOTAL 110000
#define DD 64
#define NNZ_ADJ 2000000
#define NNZ_MM 300000

// row-partition divisors: 8 equal partitions (8*13750 = 110000, 8*3750 = 30000)
#define PART_ADJ 13750
#define PART_MM  3750

typedef float          f32x4 __attribute__((ext_vector_type(4)));
typedef unsigned short u16x4 __attribute__((ext_vector_type(4)));

// ---------------- non-temporal access helpers -------------------------------
// Streaming (read-once / write-once) data must NOT allocate L2: reserve L2 for
// the scatter's partially-written ep lines and the SpMM gather tables.

__device__ __forceinline__ int   ntl(const int* p)   { return __builtin_nontemporal_load(p); }
__device__ __forceinline__ float ntl(const float* p) { return __builtin_nontemporal_load(p); }
__device__ __forceinline__ int2  ntl2(const int2* p)
{
    union { long long l; int2 v; } u;
    u.l = __builtin_nontemporal_load(reinterpret_cast<const long long*>(p));
    return u.v;
}
__device__ __forceinline__ void nts(float* p, float v) { __builtin_nontemporal_store(v, p); }

__device__ __forceinline__ unsigned short f2h(float f)
{
    __half h = __float2half(f);
    return *reinterpret_cast<unsigned short*>(&h);
}
__device__ __forceinline__ void nts_h(__half* p, float f)
{
    __builtin_nontemporal_store(f2h(f), reinterpret_cast<unsigned short*>(p));
}

// ---------------- diagnostic sentinel ---------------------------------------

__global__ void k_sentinel(float* out, float v)
{
    if (threadIdx.x == 0 && blockIdx.x == 0) out[0] = v;
}

// ======================= CSR construction ===================================

// single pass, NT reads; counters (680 KB) live in L2, atomics are L2-local
__global__ __launch_bounds__(256) void k_count_all(
    const int* __restrict__ ar, const int* __restrict__ ir,
    const int* __restrict__ tr,
    int* __restrict__ ca, int* __restrict__ ci, int* __restrict__ ct)
{
    const int total = NNZ_ADJ + 2 * NNZ_MM;
    for (int i = blockIdx.x * blockDim.x + threadIdx.x; i < total;
         i += gridDim.x * blockDim.x) {
        int r, lim; int* c;
        if (i < NNZ_ADJ)               { r = ntl(ar + i);                    c = ca; lim = N_TOTAL; }
        else if (i < NNZ_ADJ + NNZ_MM) { r = ntl(ir + (i - NNZ_ADJ));        c = ci; lim = N_ITEMS; }
        else                           { r = ntl(tr + (i - NNZ_ADJ - NNZ_MM)); c = ct; lim = N_ITEMS; }
        if ((unsigned)r < (unsigned)lim) atomicAdd(c + r, 1);
    }
}

struct ScanArg { const int4* cnt; int* rp; int* off; int n; };

// 3 blocks, one per matrix; 8 elems/thread via int4; n must be divisible by 8.
__global__ __launch_bounds__(1024) void k_scan(ScanArg a0, ScanArg a1, ScanArg a2)
{
    ScanArg A = (blockIdx.x == 0) ? a0 : (blockIdx.x == 1) ? a1 : a2;
    __shared__ int swav[16];
    __shared__ int carry;
    const int lane = threadIdx.x & 63;
    const int wid  = threadIdx.x >> 6;
    if (threadIdx.x == 0) carry = 0;
    __syncthreads();

    for (int base = 0; base < A.n; base += 8192) {
        const int i0 = base + threadIdx.x * 8;
        int4 va = make_int4(0, 0, 0, 0), vb = make_int4(0, 0, 0, 0);
        if (i0 < A.n) { va = A.cnt[i0 >> 2]; vb = A.cnt[(i0 >> 2) + 1]; }
        const int tsum = va.x + va.y + va.z + va.w + vb.x + vb.y + vb.z + vb.w;

        int x = tsum;
        #pragma unroll
        for (int o = 1; o < 64; o <<= 1) {
            int t = __shfl_up(x, o);
            if (lane >= o) x += t;
        }
        if (lane == 63) swav[wid] = x;
        __syncthreads();
        if (wid == 0) {
            int y = (lane < 16) ? swav[lane] : 0;
            #pragma unroll
            for (int o = 1; o < 16; o <<= 1) {
                int t = __shfl_up(y, o);
                if (lane >= o) y += t;
            }
            if (lane < 16) swav[lane] = y;
        }
        __syncthreads();
        const int wbase = (wid > 0) ? swav[wid - 1] : 0;
        int e = carry + wbase + (x - tsum);

        int4 pa, pb;
        pa.x = e;            pa.y = pa.x + va.x;  pa.z = pa.y + va.y;  pa.w = pa.z + va.z;
        pb.x = pa.w + va.w;  pb.y = pb.x + vb.x;  pb.z = pb.y + vb.y;  pb.w = pb.z + vb.z;
        if (i0 < A.n) {
            ((int4*)A.rp)[i0 >> 2]        = pa;
            ((int4*)A.rp)[(i0 >> 2) + 1]  = pb;
            ((int4*)A.off)[i0 >> 2]       = pa;
            ((int4*)A.off)[(i0 >> 2) + 1] = pb;
        }
        const int tot = swav[15];
        __syncthreads();
        if (threadIdx.x == 0) carry += tot;
        __syncthreads();
    }
    if (threadIdx.x == 0) A.rp[A.n] = carry;
}

// partitioned (write locality) + 4-way batched + NT reads (round 5).
__global__ __launch_bounds__(256) void k_scatter_all(
    const int* __restrict__ ar, const int* __restrict__ ac, const float* __restrict__ av,
    const int* __restrict__ ir, const int* __restrict__ ic, const float* __restrict__ iv,
    const int* __restrict__ tr, const int* __restrict__ tc, const float* __restrict__ tv,
    int* __restrict__ oa, int* __restrict__ oi, int* __restrict__ ot,
    int2* __restrict__ ea, int2* __restrict__ ei, int2* __restrict__ et)
{
    const int p     = blockIdx.x & 7;
    const int b8    = blockIdx.x >> 3;
    const int nb8   = gridDim.x >> 3;
    const int total = NNZ_ADJ + 2 * NNZ_MM;
    const int step  = nb8 * blockDim.x;

    for (int i0 = b8 * blockDim.x + threadIdx.x; i0 < total; i0 += step * 4) {
        #pragma unroll
        for (int u = 0; u < 4; ++u) {
            const int i = i0 + u * step;
            if (i >= total) break;
            int r, c, lim, part; float v; int* off; int2* ep;
            if (i < NNZ_ADJ) {
                r = ntl(ar + i);
                part = r / PART_ADJ;
                if (part != p) continue;
                c = ntl(ac + i); v = ntl(av + i); off = oa; ep = ea; lim = N_TOTAL;
            } else if (i < NNZ_ADJ + NNZ_MM) {
                const int j = i - NNZ_ADJ;
                r = ntl(ir + j);
                part = r / PART_MM;
                if (part != p) continue;
                c = ntl(ic + j); v = ntl(iv + j); off = oi; ep = ei; lim = N_ITEMS;
            } else {
                const int j = i - NNZ_ADJ - NNZ_MM;
                r = ntl(tr + j);
                part = r / PART_MM;
                if (part != p) continue;
                c = ntl(tc + j); v = ntl(tv + j); off = ot; ep = et; lim = N_ITEMS;
            }
            if ((unsigned)r >= (unsigned)lim || (unsigned)c >= (unsigned)lim) continue;
            const int pos = atomicAdd(&off[r], 1);
            ep[pos] = make_int2(c, __float_as_int(v));   // cached 8B store
        }
    }
}

// ================== gather-table abstraction ================================
// UNIFORM base + lane member: col index arrives as an SGPR (via readlane), so
// the gather compiles to saddr-form global_load (SALU address, zero per-lane
// VALU address math). Table loads stay CACHED (only data with reuse).

struct TabF32 {
    const float* x; int lane;
    typedef float Raw;
    __device__ __forceinline__ Raw raw(int c) const { return x[(size_t)c * DD + lane]; }
    __device__ __forceinline__ static float cvt(Raw r) { return r; }
};
struct TabF16 {
    const unsigned short* x; int lane;
    typedef unsigned short Raw;
    __device__ __forceinline__ Raw raw(int c) const { return x[(size_t)c * DD + lane]; }
    __device__ __forceinline__ static float cvt(Raw r) {
        __half h; *reinterpret_cast<unsigned short*>(&h) = r;
        return __half2float(h);
    }
};
struct TabEgo {   // f32 fallback for layer-1 (split user/item tables)
    const float* u; const float* it; int lane;
    typedef float Raw;
    __device__ __forceinline__ Raw raw(int c) const {
        const float* b = (c < N_USERS) ? u + (size_t)c * DD
                                       : it + (size_t)(c - N_USERS) * DD;
        return b[lane];
    }
    __device__ __forceinline__ static float cvt(Raw r) { return r; }
};

// fp16 conversion of [user_emb; item_emb] -> ego16 (item slice doubles as item table)
__global__ __launch_bounds__(256) void k_cvt(const float* __restrict__ ue,
                                             const float* __restrict__ ie,
                                             unsigned short* __restrict__ out)
{
    const int n0 = N_USERS * DD / 4;
    const int n1 = N_TOTAL * DD / 4;
    for (int i = blockIdx.x * blockDim.x + threadIdx.x; i < n1;
         i += gridDim.x * blockDim.x) {
        const f32x4 v = (i < n0)
            ? __builtin_nontemporal_load(((const f32x4*)ue) + i)
            : __builtin_nontemporal_load(((const f32x4*)ie) + (i - n0));
        u16x4 o;
        o.x = f2h(v.x); o.y = f2h(v.y); o.z = f2h(v.z); o.w = f2h(v.w);
        __builtin_nontemporal_store(o, ((u16x4*)out) + i);
    }
}

// ======================= CSR SpMM core ======================================
// Quad-row combined-range traversal (round 4) + scalar edge processing
// (round 6): edges broadcast via v_readlane into SGPRs (no ds_bpermute, no
// per-lane gather-address VALU), headers forced uniform via readfirstlane so
// all loop control is SALU.

template<typename T>
__device__ __forceinline__ void range8(const int2 e, int k0, int k1,
                                       const T& tab, float& acc)
{
    for (int k = k0; k < k1; k += 8) {
        float vs[8]; typename T::Raw xs[8];
        #pragma unroll
        for (int s = 0; s < 8; ++s) {
            const bool ok = (k + s) < k1;           // wave-uniform
            const int  ks = ok ? (k + s) : 0;       // valid lane id
            const int  cc = __builtin_amdgcn_readlane(e.x, ks);   // SGPR col
            const int  vv = __builtin_amdgcn_readlane(e.y, ks);   // SGPR val
            vs[s] = ok ? __int_as_float(vv) : 0.f;
            xs[s] = tab.raw(ok ? cc : 0);           // saddr gather
        }
        #pragma unroll
        for (int s = 0; s < 8; ++s) acc = fmaf(vs[s], T::cvt(xs[s]), acc);
    }
}

template<typename T>
__device__ __forceinline__ void csr_rows4(const int* __restrict__ rp,
                                          const int2* __restrict__ ep,
                                          const T& tab, int r0, int lane,
                                          float& oA, float& oB, float& oC, float& oD)
{
    const int4 qv = *(const int4*)(rp + r0);  // rp 16B-aligned, r0 % 4 == 0
    const int q0 = __builtin_amdgcn_readfirstlane(qv.x);
    const int q1 = __builtin_amdgcn_readfirstlane(qv.y);
    const int q2 = __builtin_amdgcn_readfirstlane(qv.z);
    const int q3 = __builtin_amdgcn_readfirstlane(qv.w);
    const int e4 = __builtin_amdgcn_readfirstlane(rp[r0 + 4]);
    float aA = 0.f, aB = 0.f, aC = 0.f, aD = 0.f;
    for (int j = q0; j < e4; j += 64) {
        const int cnt = min(64, e4 - j);
        int2 e = make_int2(0, 0);
        if (lane < cnt) e = ntl2(ep + j + lane);
        const int b1 = min(max(q1 - j, 0), cnt);
        const int b2 = min(max(q2 - j, 0), cnt);
        const int b3 = min(max(q3 - j, 0), cnt);
        range8(e, 0,  b1,  tab, aA);
        range8(e, b1, b2,  tab, aB);
        range8(e, b2, b3,  tab, aC);
        range8(e, b3, cnt, tab, aD);
    }
    oA = aA; oB = aB; oC = aC; oD = aD;
}

// -------- modality SpMM + attention fused: 4 items per wave -----------------

template<typename T>
__global__ __launch_bounds__(256) void k_mm_q(
    const int* __restrict__ rp_i, const int2* __restrict__ ep_i,
    const int* __restrict__ rp_t, const int2* __restrict__ ep_t,
    T tab,
    const float* __restrict__ Wq1, const float* __restrict__ bq1, const float* __restrict__ wq2,
    float* __restrict__ out_img, float* __restrict__ out_txt, float* __restrict__ out_h)
{
    __shared__ float sW[DD * DD];
    __shared__ float sb[DD];
    __shared__ float sq[DD];
    for (int i = threadIdx.x; i < DD * DD; i += blockDim.x) sW[i] = Wq1[i];
    if (threadIdx.x < DD) {
        sb[threadIdx.x] = bq1[threadIdx.x];
        sq[threadIdx.x] = wq2[threadIdx.x];
    }
    __syncthreads();

    const int lane = threadIdx.x & 63;
    const int i0 = (blockIdx.x * 4 + (threadIdx.x >> 6)) * 4;
    if (i0 >= N_ITEMS) return;
    tab.lane = lane;

    float iv[4], tv[4];
    csr_rows4(rp_i, ep_i, tab, i0, lane, iv[0], iv[1], iv[2], iv[3]);
    csr_rows4(rp_t, ep_t, tab, i0, lane, tv[0], tv[1], tv[2], tv[3]);
    #pragma unroll
    for (int q = 0; q < 4; ++q) {
        const size_t p = (size_t)(i0 + q) * DD + lane;
        nts(out_img + p, iv[q]);
        nts(out_txt + p, tv[q]);
    }

    // 8-stream MLP (4 items x {img, txt})
    float A0[4], A1[4];
    #pragma unroll
    for (int q = 0; q < 4; ++q) { A0[q] = sb[lane]; A1[q] = sb[lane]; }
    #pragma unroll 4
    for (int k = 0; k < DD; ++k) {
        const float w = sW[k * DD + lane];
        #pragma unroll
        for (int q = 0; q < 4; ++q) {
            A0[q] = fmaf(__shfl(iv[q], k), w, A0[q]);
            A1[q] = fmaf(__shfl(tv[q], k), w, A1[q]);
        }
    }
    #pragma unroll
    for (int q = 0; q < 4; ++q) {
        float si = tanhf(A0[q]) * sq[lane];
        float st = tanhf(A1[q]) * sq[lane];
        #pragma unroll
        for (int off = 32; off; off >>= 1) {
            si += __shfl_xor(si, off);
            st += __shfl_xor(st, off);
        }
        const float m  = fmaxf(si, st);
        const float ei = expf(si - m), et = expf(st - m);
        const size_t p = (size_t)(i0 + q) * DD + lane;
        nts(out_h + p, (ei * iv[q] + et * tv[q]) / (ei + et));
    }
}

// -------- cur1 = A * ego, 4 rows per wave; optional fp16 shadow copy --------

template<typename T, bool W16>
__global__ __launch_bounds__(256) void k_spmm_ego_q(
    const int* __restrict__ rp, const int2* __restrict__ ep, T tab,
    float* __restrict__ out, __half* __restrict__ out16)
{
    const int lane = threadIdx.x & 63;
    const int r0 = (blockIdx.x * 4 + (threadIdx.x >> 6)) * 4;
    if (r0 >= N_TOTAL) return;
    tab.lane = lane;
    float a, b, c, d;
    csr_rows4(rp, ep, tab, r0, lane, a, b, c, d);
    const size_t p = (size_t)r0 * DD + lane;
    nts(out + p,          a);
    nts(out + p + DD,     b);
    nts(out + p + 2 * DD, c);
    nts(out + p + 3 * DD, d);
    if constexpr (W16) {
        nts_h(out16 + p,          a);
        nts_h(out16 + p + DD,     b);
        nts_h(out16 + p + 2 * DD, c);
        nts_h(out16 + p + 3 * DD, d);
    }
}

// -------- fused final: role-split blocks (item blocks first, VALU-heavy) ----

#define NB_ITEM_FINAL 1875   // 1875 blocks * 4 waves * 4 rows = 30000 items
#define NB_USER_FINAL 5000   // 5000 blocks * 4 waves * 4 rows = 80000 users

template<typename T>
__global__ __launch_bounds__(256) void k_final_q(
    const int* __restrict__ rp, const int2* __restrict__ ep, T tab,
    const float* __restrict__ cur1,
    const float* __restrict__ ue, const float* __restrict__ ie,
    const float* __restrict__ h_buf,
    const float* __restrict__ Wc1, const float* __restrict__ bc1, const float* __restrict__ wc2,
    float* __restrict__ out_ug, float* __restrict__ out_ig)
{
    __shared__ float sW[DD * DD];
    __shared__ float sb[DD];
    __shared__ float sq[DD];
    const int lane = threadIdx.x & 63;
    const int wv   = threadIdx.x >> 6;
    tab.lane = lane;

    if (blockIdx.x < NB_ITEM_FINAL) {
        for (int i = threadIdx.x; i < DD * DD; i += blockDim.x) sW[i] = Wc1[i];
        if (threadIdx.x < DD) {
            sb[threadIdx.x] = bc1[threadIdx.x];
            sq[threadIdx.x] = wc2[threadIdx.x];
        }
        __syncthreads();

        const int i0 = (blockIdx.x * 4 + wv) * 4;     // item index base
        const int r0 = N_USERS + i0;
        float a[4];
        csr_rows4(rp, ep, tab, r0, lane, a[0], a[1], a[2], a[3]);

        float ig[4], hn[4];
        #pragma unroll
        for (int q = 0; q < 4; ++q) {
            const size_t pb = (size_t)(i0 + q) * DD + lane;
            const size_t gb = (size_t)(r0 + q) * DD + lane;
            ig[q] = (ntl(ie + pb) + ntl(cur1 + gb) + a[q]) * (1.0f / 3.0f);
            const float hv = ntl(h_buf + pb);
            float ss = hv * hv;
            #pragma unroll
            for (int off = 32; off; off >>= 1) ss += __shfl_xor(ss, off);
            hn[q] = hv / fmaxf(sqrtf(ss), 1e-12f);
        }

        float A0[4], A1[4];
        #pragma unroll
        for (int q = 0; q < 4; ++q) { A0[q] = sb[lane]; A1[q] = sb[lane]; }
        #pragma unroll 4
        for (int k = 0; k < DD; ++k) {
            const float w = sW[k * DD + lane];
            #pragma unroll
            for (int q = 0; q < 4; ++q) {
                A0[q] = fmaf(__shfl(ig[q], k), w, A0[q]);
                A1[q] = fmaf(__shfl(hn[q], k), w, A1[q]);
            }
        }
        #pragma unroll
        for (int q = 0; q < 4; ++q) {
            float s0 = tanhf(A0[q]) * sq[lane];
            float s1 = tanhf(A1[q]) * sq[lane];
            #pragma unroll
            for (int off = 32; off; off >>= 1) {
                s0 += __shfl_xor(s0, off);
                s1 += __shfl_xor(s1, off);
            }
            const float m  = fmaxf(s0, s1);
            const float e0 = expf(s0 - m), e1 = expf(s1 - m);
            nts(out_ig + (size_t)(i0 + q) * DD + lane,
                (e0 * ig[q] + e1 * hn[q]) / (e0 + e1));
        }
    } else {
        const int r0 = ((blockIdx.x - NB_ITEM_FINAL) * 4 + wv) * 4;   // user rows
        float a[4];
        csr_rows4(rp, ep, tab, r0, lane, a[0], a[1], a[2], a[3]);
        #pragma unroll
        for (int q = 0; q < 4; ++q) {
            const size_t gb = (size_t)(r0 + q) * DD + lane;
            nts(out_ug + gb, (ntl(ue + gb) + ntl(cur1 + gb) + a[q]) * (1.0f / 3.0f));
        }
    }
}

// ----------------------------------------------------------------------------

extern "C" void kernel_launch(void* const* d_in, const int* in_sizes, int n_in,
                              void* d_out, int out_size, void* d_ws, size_t ws_size,
                              hipStream_t stream)
{
    static const int EXP[17] = {
        N_USERS * DD, N_ITEMS * DD, DD * DD, DD, DD, DD * DD, DD, DD,
        NNZ_ADJ, NNZ_MM, NNZ_MM, NNZ_ADJ, NNZ_ADJ, NNZ_MM, NNZ_MM, NNZ_MM, NNZ_MM
    };

    float* out = (float*)d_out;

    const int OUT_EXPECT = (N_USERS + 4 * N_ITEMS) * DD;
    if (out_size != OUT_EXPECT) {
        k_sentinel<<<1, 64, 0, stream>>>(out, 5000.0f + (float)(((unsigned)out_size) >> 20));
        return;
    }
    if (n_in < 17) {
        k_sentinel<<<1, 64, 0, stream>>>(out, 1000.0f + 8.0f * (float)n_in);
        return;
    }

    int map[17];
    bool exact = true;
    for (int i = 0; i < 17; ++i) { map[i] = i; if (in_sizes[i] != EXP[i]) exact = false; }
    if (!exact) {
        bool used[64] = {false};
        for (int i = 0; i < 17; ++i) {
            int found = -1;
            for (int j = 0; j < n_in && j < 64; ++j)
                if (!used[j] && in_sizes[j] == EXP[i]) { found = j; break; }
            if (found < 0) {
                k_sentinel<<<1, 64, 0, stream>>>(out, 2000.0f + 32.0f * (float)i);
                return;
            }
            used[found] = true; map[i] = found;
        }
    }

    const float* user_emb = (const float*)d_in[map[0]];
    const float* item_emb = (const float*)d_in[map[1]];
    const float* Wq1      = (const float*)d_in[map[2]];
    const float* bq1      = (const float*)d_in[map[3]];
    const float* wq2      = (const float*)d_in[map[4]];
    const float* Wc1      = (const float*)d_in[map[5]];
    const float* bc1      = (const float*)d_in[map[6]];
    const float* wc2      = (const float*)d_in[map[7]];
    const float* adj_vals = (const float*)d_in[map[8]];
    const float* img_vals = (const float*)d_in[map[9]];
    const float* txt_vals = (const float*)d_in[map[10]];
    const int* adj_rows   = (const int*)d_in[map[11]];
    const int* adj_cols   = (const int*)d_in[map[12]];
    const int* img_rows   = (const int*)d_in[map[13]];
    const int* img_cols   = (const int*)d_in[map[14]];
    const int* txt_rows   = (const int*)d_in[map[15]];
    const int* txt_cols   = (const int*)d_in[map[16]];

    // -------- workspace layout (all 16B-aligned sections) --------
    float* cur1   = (float*)d_ws;                     // N_TOTAL*DD
    int2*  ep_adj = (int2*)(cur1 + (size_t)N_TOTAL * DD);
    int2*  ep_img = ep_adj + NNZ_ADJ;
    int2*  ep_txt = ep_img + NNZ_MM;
    int*   cnt_adj = (int*)(ep_txt + NNZ_MM);         // contiguous cnt block
    int*   cnt_img = cnt_adj + N_TOTAL;
    int*   cnt_txt = cnt_img + N_ITEMS;
    int*   rp_adj  = cnt_txt + N_ITEMS;               // padded to keep 16B align
    int*   rp_img  = rp_adj + 110004;
    int*   rp_txt  = rp_img + 30004;
    int*   off_adj = rp_txt + 30004;
    int*   off_img = off_adj + N_TOTAL;
    int*   off_txt = off_img + N_ITEMS;
    int*   i_end   = off_txt + N_ITEMS;

    size_t used_b = (size_t)((char*)i_end - (char*)d_ws);
    if (ws_size < used_b) {
        k_sentinel<<<1, 64, 0, stream>>>(out, 3000.0f + (float)(ws_size >> 20));
        return;
    }
    used_b = (used_b + 15) & ~(size_t)15;
    __half* ego16 = (__half*)((char*)d_ws + used_b);          // N_TOTAL*DD halves
    __half* cur16 = ego16 + (size_t)N_TOTAL * DD;             // N_TOTAL*DD halves
    const size_t WS_FULL = used_b + 2 * (size_t)N_TOTAL * DD * sizeof(__half);
    const bool use16 = (ws_size >= WS_FULL);

    float* out_ug  = out;
    float* out_ig  = out_ug  + (size_t)N_USERS * DD;
    float* out_img = out_ig  + (size_t)N_ITEMS * DD;
    float* out_txt = out_img + (size_t)N_ITEMS * DD;
    float* out_h   = out_txt + (size_t)N_ITEMS * DD;

    // ---- CSR build ----
    hipMemsetAsync(cnt_adj, 0, (size_t)(N_TOTAL + 2 * N_ITEMS) * sizeof(int), stream);
    k_count_all<<<2048, 256, 0, stream>>>(adj_rows, img_rows, txt_rows,
                                          cnt_adj, cnt_img, cnt_txt);

    ScanArg sa{(const int4*)cnt_adj, rp_adj, off_adj, N_TOTAL};
    ScanArg si{(const int4*)cnt_img, rp_img, off_img, N_ITEMS};
    ScanArg st{(const int4*)cnt_txt, rp_txt, off_txt, N_ITEMS};
    k_scan<<<3, 1024, 0, stream>>>(sa, si, st);

    k_scatter_all<<<2048, 256, 0, stream>>>(adj_rows, adj_cols, adj_vals,
                                            img_rows, img_cols, img_vals,
                                            txt_rows, txt_cols, txt_vals,
                                            off_adj, off_img, off_txt,
                                            ep_adj, ep_img, ep_txt);

    if (use16) {
        // fp16 gather tables: halve the L2-miss bytes on every SpMM gather
        k_cvt<<<2048, 256, 0, stream>>>(user_emb, item_emb, (unsigned short*)ego16);

        k_mm_q<TabF16><<<1875, 256, 0, stream>>>(
            rp_img, ep_img, rp_txt, ep_txt,
            TabF16{(const unsigned short*)ego16 + (size_t)N_USERS * DD, 0},
            Wq1, bq1, wq2, out_img, out_txt, out_h);

        k_spmm_ego_q<TabF16, true><<<6875, 256, 0, stream>>>(
            rp_adj, ep_adj, TabF16{(const unsigned short*)ego16, 0}, cur1, cur16);

        k_final_q<TabF16><<<NB_ITEM_FINAL + NB_USER_FINAL, 256, 0, stream>>>(
            rp_adj, ep_adj, TabF16{(const unsigned short*)cur16, 0}, cur1,
            user_emb, item_emb, out_h, Wc1, bc1, wc2, out_ug, out_ig);
    } else {
        // f32 fallback (quad traversal only)
        k_mm_q<TabF32><<<1875, 256, 0, stream>>>(
            rp_img, ep_img, rp_txt, ep_txt, TabF32{item_emb, 0},
            Wq1, bq1, wq2, out_img, out_txt, out_h);

        k_spmm_ego_q<TabEgo, false><<<6875, 256, 0, stream>>>(
            rp_adj, ep_adj, TabEgo{user_emb, item_emb, 0}, cur1, nullptr);

        k_final_q<TabF32><<<NB_ITEM_FINAL + NB_USER_FINAL, 256, 0, stream>>>(
            rp_adj, ep_adj, TabF32{cur1, 0}, cur1, user_emb, item_emb,
            out_h, Wc1, bc1, wc2, out_ug, out_ig);
    }
}